// Round 1
// baseline (1153.570 us; speedup 1.0000x reference)
//
#include <hip/hip_runtime.h>
#include <math.h>

#define NN 32768
#define NE 262144
#define NG 256
#define DIN 256
#define DH 512
#define DOUT 512

// ---------------- graph prep ----------------

__global__ void k_count(const int* __restrict__ ei, int* __restrict__ counts) {
  int e = blockIdx.x * 256 + threadIdx.x;
  if (e < NE) atomicAdd(&counts[ei[NE + e]], 1);
}

__global__ __launch_bounds__(1024) void k_scan(const int* __restrict__ counts,
                                               int* __restrict__ offs) {
  __shared__ int sums[1024];
  int tid = threadIdx.x;
  int base = tid * 32;
  int local[32];
  int s = 0;
#pragma unroll
  for (int i = 0; i < 32; ++i) { local[i] = counts[base + i]; s += local[i]; }
  sums[tid] = s;
  __syncthreads();
  for (int off = 1; off < 1024; off <<= 1) {
    int add = (tid >= off) ? sums[tid - off] : 0;
    __syncthreads();
    sums[tid] += add;
    __syncthreads();
  }
  int prefix = (tid == 0) ? 0 : sums[tid - 1];
#pragma unroll
  for (int i = 0; i < 32; ++i) { offs[base + i] = prefix; prefix += local[i]; }
  if (tid == 1023) offs[NN] = prefix;
}

__global__ void k_fill(const int* __restrict__ ei, const int* __restrict__ offs,
                       int* __restrict__ cursor, int* __restrict__ csr) {
  int e = blockIdx.x * 256 + threadIdx.x;
  if (e < NE) {
    int d = ei[NE + e];
    int pos = offs[d] + atomicAdd(&cursor[d], 1);
    csr[pos] = ei[e];
  }
}

__global__ void k_dinv(const int* __restrict__ counts, float* __restrict__ dinv) {
  int v = blockIdx.x * 256 + threadIdx.x;
  if (v < NN) dinv[v] = rsqrtf((float)(counts[v] + 1));
}

__global__ void k_starts(const int* __restrict__ batch, int* __restrict__ starts) {
  int g = threadIdx.x;
  int lo = 0, hi = NN;
  while (lo < hi) {
    int mid = (lo + hi) >> 1;
    if (batch[mid] < g) lo = mid + 1; else hi = mid;
  }
  starts[g] = lo;
  if (g == 0) starts[NG] = NN;
}

// ---------------- fp32 tiled GEMM: C[M][Nn] = A[M][K] @ B[K][Nn] ----------------
// 64x64 tile, 256 threads, 4x4 microtile. All dims divisible (M%64==0, Nn%64==0, K%16==0).

__global__ __launch_bounds__(256) void k_gemm(const float* __restrict__ A,
                                              const float* __restrict__ B,
                                              float* __restrict__ C,
                                              int M, int Nn, int K) {
  __shared__ __align__(16) float sA[16][68];
  __shared__ __align__(16) float sB[16][68];
  int tid = threadIdx.x;
  int bn = blockIdx.x * 64;
  int bm = blockIdx.y * 64;
  int tx = tid & 15, ty = tid >> 4;
  int lrow = tid >> 2, lkq = (tid & 3) << 2;   // A-tile load: row 0..63, k-quad
  int bkrow = tid >> 4, bcq = (tid & 15) << 2; // B-tile load: k-row 0..15, col-quad
  float acc[4][4] = {};
  for (int kk = 0; kk < K; kk += 16) {
    float4 av = *(const float4*)(A + (size_t)(bm + lrow) * K + kk + lkq);
    sA[lkq + 0][lrow] = av.x;
    sA[lkq + 1][lrow] = av.y;
    sA[lkq + 2][lrow] = av.z;
    sA[lkq + 3][lrow] = av.w;
    float4 bv = *(const float4*)(B + (size_t)(kk + bkrow) * Nn + bn + bcq);
    *(float4*)&sB[bkrow][bcq] = bv;
    __syncthreads();
#pragma unroll
    for (int k = 0; k < 16; ++k) {
      float4 a = *(const float4*)&sA[k][ty << 2];
      float4 b = *(const float4*)&sB[k][tx << 2];
      acc[0][0] += a.x * b.x; acc[0][1] += a.x * b.y; acc[0][2] += a.x * b.z; acc[0][3] += a.x * b.w;
      acc[1][0] += a.y * b.x; acc[1][1] += a.y * b.y; acc[1][2] += a.y * b.z; acc[1][3] += a.y * b.w;
      acc[2][0] += a.z * b.x; acc[2][1] += a.z * b.y; acc[2][2] += a.z * b.z; acc[2][3] += a.z * b.w;
      acc[3][0] += a.w * b.x; acc[3][1] += a.w * b.y; acc[3][2] += a.w * b.z; acc[3][3] += a.w * b.w;
    }
    __syncthreads();
  }
#pragma unroll
  for (int i = 0; i < 4; ++i) {
    float4 r = make_float4(acc[i][0], acc[i][1], acc[i][2], acc[i][3]);
    *(float4*)(C + (size_t)(bm + (ty << 2) + i) * Nn + bn + (tx << 2)) = r;
  }
}

// gates = [qstar | hs] @ [W_ih | W_hh]^T   (M=256, Nn=2048, K=1536)
__global__ __launch_bounds__(256) void k_gemm_gates(const float* __restrict__ qstar,
                                                    const float* __restrict__ hs,
                                                    const float* __restrict__ W_ih,
                                                    const float* __restrict__ W_hh,
                                                    float* __restrict__ gates) {
  __shared__ __align__(16) float sA[16][68];
  __shared__ __align__(16) float sB[16][68];
  int tid = threadIdx.x;
  int bn = blockIdx.x * 64;  // gate col j
  int bm = blockIdx.y * 64;  // graph row
  int tx = tid & 15, ty = tid >> 4;
  int lrow = tid >> 2, lkq = (tid & 3) << 2;
  float acc[4][4] = {};
  for (int kk = 0; kk < 1536; kk += 16) {
    int k0 = kk + lkq;
    float4 av, bv;
    if (k0 < 1024) av = *(const float4*)(qstar + (size_t)(bm + lrow) * 1024 + k0);
    else           av = *(const float4*)(hs + (size_t)(bm + lrow) * 512 + (k0 - 1024));
    sA[lkq + 0][lrow] = av.x;
    sA[lkq + 1][lrow] = av.y;
    sA[lkq + 2][lrow] = av.z;
    sA[lkq + 3][lrow] = av.w;
    if (k0 < 1024) bv = *(const float4*)(W_ih + (size_t)(bn + lrow) * 1024 + k0);
    else           bv = *(const float4*)(W_hh + (size_t)(bn + lrow) * 512 + (k0 - 1024));
    sB[lkq + 0][lrow] = bv.x;
    sB[lkq + 1][lrow] = bv.y;
    sB[lkq + 2][lrow] = bv.z;
    sB[lkq + 3][lrow] = bv.w;
    __syncthreads();
#pragma unroll
    for (int k = 0; k < 16; ++k) {
      float4 a = *(const float4*)&sA[k][ty << 2];
      float4 b = *(const float4*)&sB[k][tx << 2];
      acc[0][0] += a.x * b.x; acc[0][1] += a.x * b.y; acc[0][2] += a.x * b.z; acc[0][3] += a.x * b.w;
      acc[1][0] += a.y * b.x; acc[1][1] += a.y * b.y; acc[1][2] += a.y * b.z; acc[1][3] += a.y * b.w;
      acc[2][0] += a.z * b.x; acc[2][1] += a.z * b.y; acc[2][2] += a.z * b.z; acc[2][3] += a.z * b.w;
      acc[3][0] += a.w * b.x; acc[3][1] += a.w * b.y; acc[3][2] += a.w * b.z; acc[3][3] += a.w * b.w;
    }
    __syncthreads();
  }
#pragma unroll
  for (int i = 0; i < 4; ++i) {
    float4 r = make_float4(acc[i][0], acc[i][1], acc[i][2], acc[i][3]);
    *(float4*)(gates + (size_t)(bm + (ty << 2) + i) * 2048 + bn + (tx << 2)) = r;
  }
}

// ---------------- GCN aggregation: out[v] = dinv[v]*(sum_u dinv[u]H[u] + dinv[v]H[v]) + b ----------------
__global__ __launch_bounds__(128) void k_agg(const float* __restrict__ H,
                                             const int* __restrict__ offs,
                                             const int* __restrict__ csr,
                                             const float* __restrict__ dinv,
                                             const float* __restrict__ bias,
                                             float* __restrict__ out, int do_relu) {
  int v = blockIdx.x;
  int f = threadIdx.x << 2;
  int s = offs[v], t = offs[v + 1];
  float dv = dinv[v];
  float4 acc = make_float4(0.f, 0.f, 0.f, 0.f);
  for (int j = s; j < t; ++j) {
    int u = csr[j];
    float w = dinv[u];
    float4 hv = *(const float4*)(H + (size_t)u * DH + f);
    acc.x += w * hv.x; acc.y += w * hv.y; acc.z += w * hv.z; acc.w += w * hv.w;
  }
  float4 hv = *(const float4*)(H + (size_t)v * DH + f);
  acc.x += dv * hv.x; acc.y += dv * hv.y; acc.z += dv * hv.z; acc.w += dv * hv.w;
  float4 bb = *(const float4*)(bias + f);
  float4 r;
  r.x = acc.x * dv + bb.x;
  r.y = acc.y * dv + bb.y;
  r.z = acc.z * dv + bb.z;
  r.w = acc.w * dv + bb.w;
  if (do_relu) {
    r.x = fmaxf(r.x, 0.f); r.y = fmaxf(r.y, 0.f); r.z = fmaxf(r.z, 0.f); r.w = fmaxf(r.w, 0.f);
  }
  *(float4*)(out + (size_t)v * DH + f) = r;
}

// ---------------- LSTM elementwise ----------------
__global__ __launch_bounds__(256) void k_lstm(const float* __restrict__ gates,
                                              const float* __restrict__ b_ih,
                                              const float* __restrict__ b_hh,
                                              float* __restrict__ cs,
                                              float* __restrict__ hs,
                                              float* __restrict__ qstar) {
  int idx = blockIdx.x * 256 + threadIdx.x;  // NG*DOUT
  int g = idx >> 9, j = idx & 511;
  const float* grow = gates + (size_t)g * 2048;
  float iv = grow[j]        + b_ih[j]        + b_hh[j];
  float fv = grow[512 + j]  + b_ih[512 + j]  + b_hh[512 + j];
  float gv = grow[1024 + j] + b_ih[1024 + j] + b_hh[1024 + j];
  float ov = grow[1536 + j] + b_ih[1536 + j] + b_hh[1536 + j];
  float si = 1.f / (1.f + expf(-iv));
  float sf = 1.f / (1.f + expf(-fv));
  float so = 1.f / (1.f + expf(-ov));
  float c = sf * cs[idx] + si * tanhf(gv);
  float h = so * tanhf(c);
  cs[idx] = c;
  hs[idx] = h;
  qstar[(size_t)g * 1024 + j] = h;
}

// ---------------- e[n] = dot(H2[n], hs[batch[n]]) ----------------
__global__ __launch_bounds__(256) void k_dote(const float* __restrict__ H2,
                                              const float* __restrict__ hs,
                                              const int* __restrict__ batch,
                                              float* __restrict__ evec) {
  int n = blockIdx.x * 4 + (threadIdx.x >> 6);
  int lane = threadIdx.x & 63;
  const float* hrow = H2 + (size_t)n * DH;
  const float* qrow = hs + (size_t)batch[n] * DOUT;
  float s = 0.f;
#pragma unroll
  for (int t = 0; t < 8; ++t) s += hrow[lane + 64 * t] * qrow[lane + 64 * t];
#pragma unroll
  for (int off = 32; off > 0; off >>= 1) s += __shfl_down(s, off);
  if (lane == 0) evec[n] = s;
}

// ---------------- per-graph softmax + weighted pooling ----------------
__global__ __launch_bounds__(256) void k_pool(const float* __restrict__ evec,
                                              const float* __restrict__ H2,
                                              const int* __restrict__ starts,
                                              float* __restrict__ qstar) {
  int g = blockIdx.x;
  int s = starts[g], t = starts[g + 1];
  int tid = threadIdx.x;
  __shared__ float red[256];
  __shared__ float sa[256];
  // pass 1: max
  float m = -INFINITY;
  for (int n = s + tid; n < t; n += 256) m = fmaxf(m, evec[n]);
  red[tid] = m;
  __syncthreads();
#pragma unroll
  for (int o = 128; o > 0; o >>= 1) {
    if (tid < o) red[tid] = fmaxf(red[tid], red[tid + o]);
    __syncthreads();
  }
  float emax = red[0];
  if (!(emax > -3.0e38f)) emax = 0.f;  // empty graph -> isfinite replacement
  __syncthreads();
  // pass 2: sum exp
  float sm = 0.f;
  for (int n = s + tid; n < t; n += 256) sm += expf(evec[n] - emax);
  red[tid] = sm;
  __syncthreads();
#pragma unroll
  for (int o = 128; o > 0; o >>= 1) {
    if (tid < o) red[tid] += red[tid + o];
    __syncthreads();
  }
  float inv = 1.f / fmaxf(red[0], 1e-12f);
  __syncthreads();
  // pass 3: weighted feature sum, chunks of 256 nodes via LDS weights
  int f = tid << 1;
  float2 acc = make_float2(0.f, 0.f);
  for (int base = s; base < t; base += 256) {
    int n = base + tid;
    sa[tid] = (n < t) ? expf(evec[n] - emax) * inv : 0.f;
    __syncthreads();
    int cnt = min(256, t - base);
    for (int i = 0; i < cnt; ++i) {
      float a = sa[i];
      float2 hv = *(const float2*)(H2 + (size_t)(base + i) * DH + f);
      acc.x += a * hv.x;
      acc.y += a * hv.y;
    }
    __syncthreads();
  }
  *(float2*)(qstar + (size_t)g * 1024 + 512 + f) = acc;
}

// ---------------- launch ----------------
extern "C" void kernel_launch(void* const* d_in, const int* in_sizes, int n_in,
                              void* d_out, int out_size, void* d_ws, size_t ws_size,
                              hipStream_t stream) {
  const float* x     = (const float*)d_in[0];
  const int*   ei    = (const int*)d_in[1];
  const int*   batch = (const int*)d_in[2];
  const float* W1    = (const float*)d_in[3];
  const float* b1    = (const float*)d_in[4];
  const float* W2    = (const float*)d_in[5];
  const float* b2    = (const float*)d_in[6];
  const float* W_ih  = (const float*)d_in[7];
  const float* W_hh  = (const float*)d_in[8];
  const float* b_ih  = (const float*)d_in[9];
  const float* b_hh  = (const float*)d_in[10];
  float* qstar = (float*)d_out;

  char* w = (char*)d_ws;
  size_t off = 0;
  auto carve = [&](size_t bytes) -> void* {
    void* p = w + off;
    off += (bytes + 255) & ~(size_t)255;
    return p;
  };
  float* bufA   = (float*)carve((size_t)NN * DH * 4);   // H1lin / H2lin
  float* bufB   = (float*)carve((size_t)NN * DH * 4);   // H1 / H2
  int*   counts = (int*)carve((size_t)NN * 4);
  int*   offs   = (int*)carve((size_t)(NN + 1) * 4);
  int*   cursor = (int*)carve((size_t)NN * 4);
  int*   csr    = (int*)carve((size_t)NE * 4);
  float* dinv   = (float*)carve((size_t)NN * 4);
  float* gates  = (float*)carve((size_t)NG * 2048 * 4);
  float* hs     = (float*)carve((size_t)NG * DOUT * 4);
  float* cs     = (float*)carve((size_t)NG * DOUT * 4);
  float* evec   = (float*)carve((size_t)NN * 4);
  int*   starts = (int*)carve((size_t)(NG + 1) * 4);

  hipMemsetAsync(counts, 0, (size_t)NN * 4, stream);
  hipMemsetAsync(cursor, 0, (size_t)NN * 4, stream);
  hipMemsetAsync(hs, 0, (size_t)NG * DOUT * 4, stream);
  hipMemsetAsync(cs, 0, (size_t)NG * DOUT * 4, stream);
  hipMemsetAsync(qstar, 0, (size_t)NG * 1024 * 4, stream);

  k_count<<<NE / 256, 256, 0, stream>>>(ei, counts);
  k_scan<<<1, 1024, 0, stream>>>(counts, offs);
  k_fill<<<NE / 256, 256, 0, stream>>>(ei, offs, cursor, csr);
  k_dinv<<<NN / 256, 256, 0, stream>>>(counts, dinv);
  k_starts<<<1, NG, 0, stream>>>(batch, starts);

  // GCN layer 1: H1 = relu(Agg(x@W1) + b1)
  k_gemm<<<dim3(DH / 64, NN / 64), 256, 0, stream>>>(x, W1, bufA, NN, DH, DIN);
  k_agg<<<NN, 128, 0, stream>>>(bufA, offs, csr, dinv, b1, bufB, 1);
  // GCN layer 2: H2 = Agg(H1@W2) + b2
  k_gemm<<<dim3(DH / 64, NN / 64), 256, 0, stream>>>(bufB, W2, bufA, NN, DH, DH);
  k_agg<<<NN, 128, 0, stream>>>(bufA, offs, csr, dinv, b2, bufB, 0);

  for (int step = 0; step < 3; ++step) {
    k_gemm_gates<<<dim3(2048 / 64, NG / 64), 256, 0, stream>>>(qstar, hs, W_ih, W_hh, gates);
    k_lstm<<<(NG * DOUT) / 256, 256, 0, stream>>>(gates, b_ih, b_hh, cs, hs, qstar);
    k_dote<<<NN / 4, 256, 0, stream>>>(bufB, hs, batch, evec);
    k_pool<<<NG, 256, 0, stream>>>(evec, bufB, starts, qstar);
  }
}

// Round 2
// 620.163 us; speedup vs baseline: 1.8601x; 1.8601x over previous
//
#include <hip/hip_runtime.h>
#include <math.h>

#define NN 32768
#define NE 262144
#define NG 256
#define DIN 256
#define DH 512
#define DOUT 512

typedef unsigned short u16;
typedef __attribute__((ext_vector_type(8))) short short8;
typedef __attribute__((ext_vector_type(4))) float f32x4;

__device__ inline u16 bf16rn(float f) {
  unsigned u = __float_as_uint(f);
  return (u16)((u + 0x7fff + ((u >> 16) & 1)) >> 16);
}
__device__ inline float bfbits(u16 b) { return __uint_as_float(((unsigned)b) << 16); }
__device__ inline void split2(float f, u16& h, u16& l) {
  h = bf16rn(f);
  float r = f - bfbits(h);
  l = bf16rn(r);
}

__device__ inline void gload16(const void* g, void* l) {
  __builtin_amdgcn_global_load_lds((const __attribute__((address_space(1))) unsigned int*)g,
                                   (__attribute__((address_space(3))) unsigned int*)l,
                                   16, 0, 0);
}

// ---------------- graph prep ----------------

__global__ void k_count(const int* __restrict__ ei, int* __restrict__ counts) {
  int e = blockIdx.x * 256 + threadIdx.x;
  if (e < NE) atomicAdd(&counts[ei[NE + e]], 1);
}

__global__ __launch_bounds__(1024) void k_scan(const int* __restrict__ counts,
                                               int* __restrict__ offs) {
  __shared__ int sums[1024];
  int tid = threadIdx.x;
  int base = tid * 32;
  int local[32];
  int s = 0;
#pragma unroll
  for (int i = 0; i < 32; ++i) { local[i] = counts[base + i]; s += local[i]; }
  sums[tid] = s;
  __syncthreads();
  for (int off = 1; off < 1024; off <<= 1) {
    int add = (tid >= off) ? sums[tid - off] : 0;
    __syncthreads();
    sums[tid] += add;
    __syncthreads();
  }
  int prefix = (tid == 0) ? 0 : sums[tid - 1];
#pragma unroll
  for (int i = 0; i < 32; ++i) { offs[base + i] = prefix; prefix += local[i]; }
  if (tid == 1023) offs[NN] = prefix;
}

__global__ void k_fill(const int* __restrict__ ei, const int* __restrict__ offs,
                       int* __restrict__ cursor, int* __restrict__ csr) {
  int e = blockIdx.x * 256 + threadIdx.x;
  if (e < NE) {
    int d = ei[NE + e];
    int pos = offs[d] + atomicAdd(&cursor[d], 1);
    csr[pos] = ei[e];
  }
}

__global__ void k_dinv(const int* __restrict__ counts, float* __restrict__ dinv) {
  int v = blockIdx.x * 256 + threadIdx.x;
  if (v < NN) dinv[v] = rsqrtf((float)(counts[v] + 1));
}

__global__ void k_starts(const int* __restrict__ batch, int* __restrict__ starts) {
  int g = threadIdx.x;
  int lo = 0, hi = NN;
  while (lo < hi) {
    int mid = (lo + hi) >> 1;
    if (batch[mid] < g) lo = mid + 1; else hi = mid;
  }
  starts[g] = lo;
  if (g == 0) starts[NG] = NN;
}

// ---------------- fp32 -> bf16 hi/lo split (optionally into a wider dst with col offset) ----------------
__global__ void k_split(const float* __restrict__ src, u16* __restrict__ hi, u16* __restrict__ lo,
                        int src_cols, int dst_ld, int col_off, int total) {
  int idx = blockIdx.x * 256 + threadIdx.x;
  if (idx >= total) return;
  int r = idx / src_cols, c = idx - r * src_cols;
  u16 h, l;
  split2(src[idx], h, l);
  size_t d = (size_t)r * dst_ld + col_off + c;
  hi[d] = h; lo[d] = l;
}

// transpose split: src [K][N] fp32 -> dst [N][K] bf16 hi/lo
__global__ void k_split_t(const float* __restrict__ src, u16* __restrict__ hi, u16* __restrict__ lo,
                          int K, int N, int total) {
  int idx = blockIdx.x * 256 + threadIdx.x;
  if (idx >= total) return;
  int k = idx / N, n = idx - k * N;
  u16 h, l;
  split2(src[idx], h, l);
  size_t d = (size_t)n * K + k;
  hi[d] = h; lo[d] = l;
}

// ---------------- split-bf16 MFMA GEMM ----------------
// C[M][N] = A[M][K] @ Bt[N][K]^T, A/Bt given as bf16 hi/lo pairs (row-major).
// 128x128 tile, BK=64, 256 threads (4 waves, 2x2), XOR-swizzled LDS via pre-swizzled
// global source for global_load_lds. 3-product split: hi*hi + hi*lo + lo*hi.
// Output either fp32 C, or bf16 hi/lo pair (Chi/Clo != null).
__global__ __launch_bounds__(256) void k_mfma_gemm(
    const u16* __restrict__ Ahi, const u16* __restrict__ Alo,
    const u16* __restrict__ Bhi, const u16* __restrict__ Blo,
    float* __restrict__ C, u16* __restrict__ Chi, u16* __restrict__ Clo,
    int M, int N, int K) {
  __shared__ char lds[65536];  // A_hi 16K | A_lo 16K | B_hi 16K | B_lo 16K

  int nbn = N >> 7;
  int nwg = (M >> 7) * nbn;
  int b = blockIdx.x;
  int swz = (b & 7) * (nwg >> 3) + (b >> 3);  // nwg % 8 == 0 always here
  int bn = (swz % nbn) << 7;
  int bm = (swz / nbn) << 7;

  int tid = threadIdx.x;
  int w = tid >> 6, lane = tid & 63;
  int wm = (w >> 1) << 6, wn = (w & 1) << 6;
  int fr = lane & 15;   // row within 16-frag
  int fq = lane >> 4;   // k-quad (0..3)

  f32x4 acc[4][4];
#pragma unroll
  for (int i = 0; i < 4; ++i)
#pragma unroll
    for (int j = 0; j < 4; ++j) acc[i][j] = (f32x4){0.f, 0.f, 0.f, 0.f};

  for (int ks = 0; ks < K; ks += 64) {
    // stage 4 tiles of 16KB each; tile layout [128 rows][64 k-elems] bf16,
    // 16B slot s within row holds logical slot (s ^ (row&7))  (T2 swizzle)
#pragma unroll
    for (int i = 0; i < 4; ++i) {
      int L = i * 256 + tid;
      int row = L >> 3;
      int ke = ((L & 7) ^ (row & 7)) << 3;  // logical k-element start
      int ldsoff = i * 4096 + w * 1024;     // wave-uniform base
      gload16(Ahi + (size_t)(bm + row) * K + ks + ke, lds + ldsoff);
      gload16(Alo + (size_t)(bm + row) * K + ks + ke, lds + 16384 + ldsoff);
      gload16(Bhi + (size_t)(bn + row) * K + ks + ke, lds + 32768 + ldsoff);
      gload16(Blo + (size_t)(bn + row) * K + ks + ke, lds + 49152 + ldsoff);
    }
    __syncthreads();
#pragma unroll
    for (int kk = 0; kk < 2; ++kk) {
      short8 ah[4], al[4], bh[4], bl[4];
#pragma unroll
      for (int m = 0; m < 4; ++m) {
        int row = wm + m * 16 + fr;
        int boff = row * 128 + (((kk << 6) + (fq << 4)) ^ ((row & 7) << 4));
        ah[m] = *(const short8*)(lds + boff);
        al[m] = *(const short8*)(lds + 16384 + boff);
      }
#pragma unroll
      for (int n = 0; n < 4; ++n) {
        int row = wn + n * 16 + fr;
        int boff = row * 128 + (((kk << 6) + (fq << 4)) ^ ((row & 7) << 4));
        bh[n] = *(const short8*)(lds + 32768 + boff);
        bl[n] = *(const short8*)(lds + 49152 + boff);
      }
#pragma unroll
      for (int m = 0; m < 4; ++m)
#pragma unroll
        for (int n = 0; n < 4; ++n) {
          acc[m][n] = __builtin_amdgcn_mfma_f32_16x16x32_bf16(ah[m], bh[n], acc[m][n], 0, 0, 0);
          acc[m][n] = __builtin_amdgcn_mfma_f32_16x16x32_bf16(ah[m], bl[n], acc[m][n], 0, 0, 0);
          acc[m][n] = __builtin_amdgcn_mfma_f32_16x16x32_bf16(al[m], bh[n], acc[m][n], 0, 0, 0);
        }
    }
    __syncthreads();
  }
  // C/D layout: col = lane&15, row = (lane>>4)*4 + i
#pragma unroll
  for (int m = 0; m < 4; ++m)
#pragma unroll
    for (int n = 0; n < 4; ++n)
#pragma unroll
      for (int i = 0; i < 4; ++i) {
        int r = bm + wm + m * 16 + fq * 4 + i;
        int c = bn + wn + n * 16 + fr;
        if (Chi) {
          u16 h, l;
          split2(acc[m][n][i], h, l);
          Chi[(size_t)r * N + c] = h;
          Clo[(size_t)r * N + c] = l;
        } else {
          C[(size_t)r * N + c] = acc[m][n][i];
        }
      }
}

// ---------------- GCN aggregation over bf16 hi/lo input ----------------
// out[v] = dinv[v]*(sum_u dinv[u]*H[u] + dinv[v]*H[v]) + b ; H[u] = hi+lo (exact-ish fp32)
__global__ __launch_bounds__(128) void k_agg(const u16* __restrict__ Hhi, const u16* __restrict__ Hlo,
                                             const int* __restrict__ offs,
                                             const int* __restrict__ csr,
                                             const float* __restrict__ dinv,
                                             const float* __restrict__ bias,
                                             float* __restrict__ outf,
                                             u16* __restrict__ ohi, u16* __restrict__ olo,
                                             int do_relu) {
  int v = blockIdx.x;
  int f = threadIdx.x << 2;
  int s = offs[v], t = offs[v + 1];
  float dv = dinv[v];
  float a0 = 0.f, a1 = 0.f, a2 = 0.f, a3 = 0.f;
  for (int j = s; j <= t; ++j) {
    int u = (j < t) ? csr[j] : v;
    float wgt = (j < t) ? dinv[u] : dv;
    uint2 ph = *(const uint2*)(Hhi + (size_t)u * DH + f);
    uint2 pl = *(const uint2*)(Hlo + (size_t)u * DH + f);
    float h0 = __uint_as_float((ph.x & 0xffffu) << 16) + __uint_as_float((pl.x & 0xffffu) << 16);
    float h1 = __uint_as_float(ph.x & 0xffff0000u) + __uint_as_float(pl.x & 0xffff0000u);
    float h2 = __uint_as_float((ph.y & 0xffffu) << 16) + __uint_as_float((pl.y & 0xffffu) << 16);
    float h3 = __uint_as_float(ph.y & 0xffff0000u) + __uint_as_float(pl.y & 0xffff0000u);
    a0 += wgt * h0; a1 += wgt * h1; a2 += wgt * h2; a3 += wgt * h3;
  }
  float4 bb = *(const float4*)(bias + f);
  float r0 = a0 * dv + bb.x, r1 = a1 * dv + bb.y, r2 = a2 * dv + bb.z, r3 = a3 * dv + bb.w;
  if (do_relu) {
    r0 = fmaxf(r0, 0.f); r1 = fmaxf(r1, 0.f); r2 = fmaxf(r2, 0.f); r3 = fmaxf(r3, 0.f);
  }
  if (outf) {
    *(float4*)(outf + (size_t)v * DH + f) = make_float4(r0, r1, r2, r3);
  }
  if (ohi) {
    u16 h0_, l0_, h1_, l1_, h2_, l2_, h3_, l3_;
    split2(r0, h0_, l0_); split2(r1, h1_, l1_); split2(r2, h2_, l2_); split2(r3, h3_, l3_);
    uint2 vh, vl;
    vh.x = (unsigned)h0_ | ((unsigned)h1_ << 16);
    vh.y = (unsigned)h2_ | ((unsigned)h3_ << 16);
    vl.x = (unsigned)l0_ | ((unsigned)l1_ << 16);
    vl.y = (unsigned)l2_ | ((unsigned)l3_ << 16);
    *(uint2*)(ohi + (size_t)v * DH + f) = vh;
    *(uint2*)(olo + (size_t)v * DH + f) = vl;
  }
}

// ---------------- LSTM elementwise ----------------
__global__ __launch_bounds__(256) void k_lstm(const float* __restrict__ gates,
                                              const float* __restrict__ b_ih,
                                              const float* __restrict__ b_hh,
                                              float* __restrict__ cs,
                                              float* __restrict__ hs,
                                              float* __restrict__ qstar) {
  int idx = blockIdx.x * 256 + threadIdx.x;
  int g = idx >> 9, j = idx & 511;
  const float* grow = gates + (size_t)g * 2048;
  float iv = grow[j]        + b_ih[j]        + b_hh[j];
  float fv = grow[512 + j]  + b_ih[512 + j]  + b_hh[512 + j];
  float gv = grow[1024 + j] + b_ih[1024 + j] + b_hh[1024 + j];
  float ov = grow[1536 + j] + b_ih[1536 + j] + b_hh[1536 + j];
  float si = 1.f / (1.f + expf(-iv));
  float sf = 1.f / (1.f + expf(-fv));
  float so = 1.f / (1.f + expf(-ov));
  float c = sf * cs[idx] + si * tanhf(gv);
  float h = so * tanhf(c);
  cs[idx] = c;
  hs[idx] = h;
  qstar[(size_t)g * 1024 + j] = h;
}

// ---------------- e[n] = dot(H2[n], hs[batch[n]]) ----------------
__global__ __launch_bounds__(256) void k_dote(const float* __restrict__ H2,
                                              const float* __restrict__ hs,
                                              const int* __restrict__ batch,
                                              float* __restrict__ evec) {
  int n = blockIdx.x * 4 + (threadIdx.x >> 6);
  int lane = threadIdx.x & 63;
  const float* hrow = H2 + (size_t)n * DH;
  const float* qrow = hs + (size_t)batch[n] * DOUT;
  float s = 0.f;
#pragma unroll
  for (int t = 0; t < 8; ++t) s += hrow[lane + 64 * t] * qrow[lane + 64 * t];
#pragma unroll
  for (int off = 32; off > 0; off >>= 1) s += __shfl_down(s, off);
  if (lane == 0) evec[n] = s;
}

// ---------------- per-graph softmax + weighted pooling ----------------
__global__ __launch_bounds__(256) void k_pool(const float* __restrict__ evec,
                                              const float* __restrict__ H2,
                                              const int* __restrict__ starts,
                                              float* __restrict__ qstar) {
  int g = blockIdx.x;
  int s = starts[g], t = starts[g + 1];
  int tid = threadIdx.x;
  __shared__ float red[256];
  __shared__ float sa[256];
  float m = -INFINITY;
  for (int n = s + tid; n < t; n += 256) m = fmaxf(m, evec[n]);
  red[tid] = m;
  __syncthreads();
#pragma unroll
  for (int o = 128; o > 0; o >>= 1) {
    if (tid < o) red[tid] = fmaxf(red[tid], red[tid + o]);
    __syncthreads();
  }
  float emax = red[0];
  if (!(emax > -3.0e38f)) emax = 0.f;
  __syncthreads();
  float sm = 0.f;
  for (int n = s + tid; n < t; n += 256) sm += expf(evec[n] - emax);
  red[tid] = sm;
  __syncthreads();
#pragma unroll
  for (int o = 128; o > 0; o >>= 1) {
    if (tid < o) red[tid] += red[tid + o];
    __syncthreads();
  }
  float inv = 1.f / fmaxf(red[0], 1e-12f);
  __syncthreads();
  int f = tid << 1;
  float2 acc = make_float2(0.f, 0.f);
  for (int base = s; base < t; base += 256) {
    int n = base + tid;
    sa[tid] = (n < t) ? expf(evec[n] - emax) * inv : 0.f;
    __syncthreads();
    int cnt = min(256, t - base);
    for (int i = 0; i < cnt; ++i) {
      float a = sa[i];
      float2 hv = *(const float2*)(H2 + (size_t)(base + i) * DH + f);
      acc.x += a * hv.x;
      acc.y += a * hv.y;
    }
    __syncthreads();
  }
  *(float2*)(qstar + (size_t)g * 1024 + 512 + f) = acc;
}

// ---------------- launch ----------------
extern "C" void kernel_launch(void* const* d_in, const int* in_sizes, int n_in,
                              void* d_out, int out_size, void* d_ws, size_t ws_size,
                              hipStream_t stream) {
  const float* x     = (const float*)d_in[0];
  const int*   ei    = (const int*)d_in[1];
  const int*   batch = (const int*)d_in[2];
  const float* W1    = (const float*)d_in[3];
  const float* b1    = (const float*)d_in[4];
  const float* W2    = (const float*)d_in[5];
  const float* b2    = (const float*)d_in[6];
  const float* W_ih  = (const float*)d_in[7];
  const float* W_hh  = (const float*)d_in[8];
  const float* b_ih  = (const float*)d_in[9];
  const float* b_hh  = (const float*)d_in[10];
  float* qstar = (float*)d_out;

  char* w = (char*)d_ws;
  size_t off = 0;
  auto carve = [&](size_t bytes) -> void* {
    void* p = w + off;
    off += (bytes + 255) & ~(size_t)255;
    return p;
  };
  float* bufB  = (float*)carve((size_t)NN * DH * 4);       // H2 fp32
  u16* thi     = (u16*)carve((size_t)NN * DH * 2);         // GEMM out hi
  u16* tlo     = (u16*)carve((size_t)NN * DH * 2);
  u16* h1hi    = (u16*)carve((size_t)NN * DH * 2);         // H1 hi/lo
  u16* h1lo    = (u16*)carve((size_t)NN * DH * 2);
  u16* xhi     = (u16*)carve((size_t)NN * DIN * 2);
  u16* xlo     = (u16*)carve((size_t)NN * DIN * 2);
  u16* w1thi   = (u16*)carve((size_t)DH * DIN * 2);
  u16* w1tlo   = (u16*)carve((size_t)DH * DIN * 2);
  u16* w2thi   = (u16*)carve((size_t)DH * DH * 2);
  u16* w2tlo   = (u16*)carve((size_t)DH * DH * 2);
  u16* wghi    = (u16*)carve((size_t)2048 * 1536 * 2);
  u16* wglo    = (u16*)carve((size_t)2048 * 1536 * 2);
  u16* qhhi    = (u16*)carve((size_t)NG * 1536 * 2);
  u16* qhlo    = (u16*)carve((size_t)NG * 1536 * 2);
  int* counts  = (int*)carve((size_t)NN * 4);
  int* offs    = (int*)carve((size_t)(NN + 1) * 4);
  int* cursor  = (int*)carve((size_t)NN * 4);
  int* csr     = (int*)carve((size_t)NE * 4);
  float* dinv  = (float*)carve((size_t)NN * 4);
  float* gates = (float*)carve((size_t)NG * 2048 * 4);
  float* hs    = (float*)carve((size_t)NG * DOUT * 4);
  float* cs    = (float*)carve((size_t)NG * DOUT * 4);
  float* evec  = (float*)carve((size_t)NN * 4);
  int* starts  = (int*)carve((size_t)(NG + 1) * 4);

  hipMemsetAsync(counts, 0, (size_t)NN * 4, stream);
  hipMemsetAsync(cursor, 0, (size_t)NN * 4, stream);
  hipMemsetAsync(hs, 0, (size_t)NG * DOUT * 4, stream);
  hipMemsetAsync(cs, 0, (size_t)NG * DOUT * 4, stream);
  hipMemsetAsync(qstar, 0, (size_t)NG * 1024 * 4, stream);

  k_count<<<NE / 256, 256, 0, stream>>>(ei, counts);
  k_scan<<<1, 1024, 0, stream>>>(counts, offs);
  k_fill<<<NE / 256, 256, 0, stream>>>(ei, offs, cursor, csr);
  k_dinv<<<NN / 256, 256, 0, stream>>>(counts, dinv);
  k_starts<<<1, NG, 0, stream>>>(batch, starts);

  // splits
  k_split<<<(NN * DIN + 255) / 256, 256, 0, stream>>>(x, xhi, xlo, DIN, DIN, 0, NN * DIN);
  k_split_t<<<(DIN * DH + 255) / 256, 256, 0, stream>>>(W1, w1thi, w1tlo, DIN, DH, DIN * DH);
  k_split_t<<<(DH * DH + 255) / 256, 256, 0, stream>>>(W2, w2thi, w2tlo, DH, DH, DH * DH);
  k_split<<<(2048 * 1024 + 255) / 256, 256, 0, stream>>>(W_ih, wghi, wglo, 1024, 1536, 0, 2048 * 1024);
  k_split<<<(2048 * 512 + 255) / 256, 256, 0, stream>>>(W_hh, wghi, wglo, 512, 1536, 1024, 2048 * 512);

  // GCN layer 1: t = x@W1 ; H1 = relu(Agg(t)+b1) -> bf16 hi/lo
  k_mfma_gemm<<<(NN / 128) * (DH / 128), 256, 0, stream>>>(
      xhi, xlo, w1thi, w1tlo, nullptr, thi, tlo, NN, DH, DIN);
  k_agg<<<NN, 128, 0, stream>>>(thi, tlo, offs, csr, dinv, b1, nullptr, h1hi, h1lo, 1);
  // GCN layer 2: t = H1@W2 ; H2 = Agg(t)+b2 -> fp32
  k_mfma_gemm<<<(NN / 128) * (DH / 128), 256, 0, stream>>>(
      h1hi, h1lo, w2thi, w2tlo, nullptr, thi, tlo, NN, DH, DH);
  k_agg<<<NN, 128, 0, stream>>>(thi, tlo, offs, csr, dinv, b2, bufB, nullptr, nullptr, 0);

  for (int step = 0; step < 3; ++step) {
    k_split<<<(NG * 1024 + 255) / 256, 256, 0, stream>>>(qstar, qhhi, qhlo, 1024, 1536, 0, NG * 1024);
    k_split<<<(NG * 512 + 255) / 256, 256, 0, stream>>>(hs, qhhi, qhlo, 512, 1536, 1024, NG * 512);
    k_mfma_gemm<<<(NG / 128) * (2048 / 128), 256, 0, stream>>>(
        qhhi, qhlo, wghi, wglo, gates, nullptr, nullptr, NG, 2048, 1536);
    k_lstm<<<(NG * DOUT) / 256, 256, 0, stream>>>(gates, b_ih, b_hh, cs, hs, qstar);
    k_dote<<<NN / 4, 256, 0, stream>>>(bufB, hs, batch, evec);
    k_pool<<<NG, 256, 0, stream>>>(evec, bufB, starts, qstar);
  }
}

// Round 3
// 538.884 us; speedup vs baseline: 2.1407x; 1.1508x over previous
//
#include <hip/hip_runtime.h>
#include <math.h>

#define NN 32768
#define NE 262144
#define NG 256
#define DIN 256
#define DH 512
#define DOUT 512

typedef unsigned short u16;
typedef _Float16 f16;
typedef __attribute__((ext_vector_type(2))) _Float16 f16x2;
typedef __attribute__((ext_vector_type(4))) _Float16 f16x4;
typedef __attribute__((ext_vector_type(8))) short short8;
typedef __attribute__((ext_vector_type(4))) float f32x4;

__device__ inline u16 bf16rn(float f) {
  unsigned u = __float_as_uint(f);
  return (u16)((u + 0x7fff + ((u >> 16) & 1)) >> 16);
}
__device__ inline float bfbits(u16 b) { return __uint_as_float(((unsigned)b) << 16); }
__device__ inline void split2(float f, u16& h, u16& l) {
  h = bf16rn(f);
  float r = f - bfbits(h);
  l = bf16rn(r);
}

__device__ inline void gload16(const void* g, void* l) {
  __builtin_amdgcn_global_load_lds((const __attribute__((address_space(1))) unsigned int*)g,
                                   (__attribute__((address_space(3))) unsigned int*)l,
                                   16, 0, 0);
}

// ---------------- graph prep ----------------

__global__ void k_count(const int* __restrict__ ei, int* __restrict__ counts) {
  int e = blockIdx.x * 256 + threadIdx.x;
  if (e < NE) atomicAdd(&counts[ei[NE + e]], 1);
}

__global__ __launch_bounds__(1024) void k_scan(const int* __restrict__ counts,
                                               int* __restrict__ offs) {
  __shared__ int sums[1024];
  int tid = threadIdx.x;
  int base = tid * 32;
  int local[32];
  int s = 0;
#pragma unroll
  for (int i = 0; i < 32; ++i) { local[i] = counts[base + i]; s += local[i]; }
  sums[tid] = s;
  __syncthreads();
  for (int off = 1; off < 1024; off <<= 1) {
    int add = (tid >= off) ? sums[tid - off] : 0;
    __syncthreads();
    sums[tid] += add;
    __syncthreads();
  }
  int prefix = (tid == 0) ? 0 : sums[tid - 1];
#pragma unroll
  for (int i = 0; i < 32; ++i) { offs[base + i] = prefix; prefix += local[i]; }
  if (tid == 1023) offs[NN] = prefix;
}

__global__ void k_fill(const int* __restrict__ ei, const int* __restrict__ offs,
                       int* __restrict__ cursor, int* __restrict__ csr) {
  int e = blockIdx.x * 256 + threadIdx.x;
  if (e < NE) {
    int d = ei[NE + e];
    int pos = offs[d] + atomicAdd(&cursor[d], 1);
    csr[pos] = ei[e];
  }
}

__global__ void k_dinv(const int* __restrict__ counts, float* __restrict__ dinv) {
  int v = blockIdx.x * 256 + threadIdx.x;
  if (v < NN) dinv[v] = rsqrtf((float)(counts[v] + 1));
}

__global__ void k_starts(const int* __restrict__ batch, int* __restrict__ starts) {
  int g = threadIdx.x;
  int lo = 0, hi = NN;
  while (lo < hi) {
    int mid = (lo + hi) >> 1;
    if (batch[mid] < g) lo = mid + 1; else hi = mid;
  }
  starts[g] = lo;
  if (g == 0) starts[NG] = NN;
}

// ---------------- conversions ----------------

__global__ void k_half(const float* __restrict__ src, f16* __restrict__ dst) {
  int i = (blockIdx.x * 256 + threadIdx.x) << 2;
  float4 v = *(const float4*)(src + i);
  f16x4 h = {(f16)v.x, (f16)v.y, (f16)v.z, (f16)v.w};
  *(f16x4*)(dst + i) = h;
}

__global__ void k_split(const float* __restrict__ src, u16* __restrict__ hi, u16* __restrict__ lo,
                        int src_cols, int dst_ld, int col_off, int total) {
  int idx = blockIdx.x * 256 + threadIdx.x;
  if (idx >= total) return;
  int r = idx / src_cols, c = idx - r * src_cols;
  u16 h, l;
  split2(src[idx], h, l);
  size_t d = (size_t)r * dst_ld + col_off + c;
  hi[d] = h; lo[d] = l;
}

// transpose split: src [K][N] fp32 -> dst [N][K] bf16 hi/lo
__global__ void k_split_t(const float* __restrict__ src, u16* __restrict__ hi, u16* __restrict__ lo,
                          int K, int N, int total) {
  int idx = blockIdx.x * 256 + threadIdx.x;
  if (idx >= total) return;
  int k = idx / N, n = idx - k * N;
  u16 h, l;
  split2(src[idx], h, l);
  size_t d = (size_t)n * K + k;
  hi[d] = h; lo[d] = l;
}

// ---------------- split-bf16 MFMA GEMM ----------------
// C[M][N] = A[M][K] @ Bt[N][K]^T. MODE 0: fp32 C. MODE 1: +bias, relu, split->Chi/Clo.
// MODE 2: fp16 out. 128x128 tile, BK=64, 4 waves, XOR-swizzled LDS (pre-swizzled source).
template <int MODE>
__global__ __launch_bounds__(256) void k_mfma_gemm(
    const u16* __restrict__ Ahi, const u16* __restrict__ Alo,
    const u16* __restrict__ Bhi, const u16* __restrict__ Blo,
    float* __restrict__ C, u16* __restrict__ Chi, u16* __restrict__ Clo,
    f16* __restrict__ Cf16, const float* __restrict__ bias,
    int M, int N, int K) {
  __shared__ char lds[65536];

  int nbn = N >> 7;
  int nwg = (M >> 7) * nbn;
  int b = blockIdx.x;
  int swz = (b & 7) * (nwg >> 3) + (b >> 3);  // nwg % 8 == 0 for all our shapes
  int bn = (swz % nbn) << 7;
  int bm = (swz / nbn) << 7;

  int tid = threadIdx.x;
  int w = tid >> 6, lane = tid & 63;
  int wm = (w >> 1) << 6, wn = (w & 1) << 6;
  int fr = lane & 15;
  int fq = lane >> 4;

  f32x4 acc[4][4];
#pragma unroll
  for (int i = 0; i < 4; ++i)
#pragma unroll
    for (int j = 0; j < 4; ++j) acc[i][j] = (f32x4){0.f, 0.f, 0.f, 0.f};

  for (int ks = 0; ks < K; ks += 64) {
#pragma unroll
    for (int i = 0; i < 4; ++i) {
      int L = i * 256 + tid;
      int row = L >> 3;
      int ke = ((L & 7) ^ (row & 7)) << 3;
      int ldsoff = i * 4096 + w * 1024;
      gload16(Ahi + (size_t)(bm + row) * K + ks + ke, lds + ldsoff);
      gload16(Alo + (size_t)(bm + row) * K + ks + ke, lds + 16384 + ldsoff);
      gload16(Bhi + (size_t)(bn + row) * K + ks + ke, lds + 32768 + ldsoff);
      gload16(Blo + (size_t)(bn + row) * K + ks + ke, lds + 49152 + ldsoff);
    }
    __syncthreads();
#pragma unroll
    for (int kk = 0; kk < 2; ++kk) {
      short8 ah[4], al[4], bh[4], bl[4];
#pragma unroll
      for (int m = 0; m < 4; ++m) {
        int row = wm + m * 16 + fr;
        int boff = row * 128 + (((kk << 6) + (fq << 4)) ^ ((row & 7) << 4));
        ah[m] = *(const short8*)(lds + boff);
        al[m] = *(const short8*)(lds + 16384 + boff);
      }
#pragma unroll
      for (int n = 0; n < 4; ++n) {
        int row = wn + n * 16 + fr;
        int boff = row * 128 + (((kk << 6) + (fq << 4)) ^ ((row & 7) << 4));
        bh[n] = *(const short8*)(lds + 32768 + boff);
        bl[n] = *(const short8*)(lds + 49152 + boff);
      }
#pragma unroll
      for (int m = 0; m < 4; ++m)
#pragma unroll
        for (int n = 0; n < 4; ++n) {
          acc[m][n] = __builtin_amdgcn_mfma_f32_16x16x32_bf16(ah[m], bh[n], acc[m][n], 0, 0, 0);
          acc[m][n] = __builtin_amdgcn_mfma_f32_16x16x32_bf16(ah[m], bl[n], acc[m][n], 0, 0, 0);
          acc[m][n] = __builtin_amdgcn_mfma_f32_16x16x32_bf16(al[m], bh[n], acc[m][n], 0, 0, 0);
        }
    }
    __syncthreads();
  }
#pragma unroll
  for (int m = 0; m < 4; ++m)
#pragma unroll
    for (int n = 0; n < 4; ++n)
#pragma unroll
      for (int i = 0; i < 4; ++i) {
        int r = bm + wm + m * 16 + fq * 4 + i;
        int c = bn + wn + n * 16 + fr;
        float val = acc[m][n][i];
        if (MODE == 1) {
          val += bias[c];
          val = fmaxf(val, 0.f);
          u16 h, l;
          split2(val, h, l);
          Chi[(size_t)r * N + c] = h;
          Clo[(size_t)r * N + c] = l;
        } else if (MODE == 2) {
          Cf16[(size_t)r * N + c] = (f16)val;
        } else {
          C[(size_t)r * N + c] = val;
        }
      }
}

// ---------------- aggregation, 256-dim fp16 in -> bf16 hi/lo out ----------------
__global__ __launch_bounds__(256) void k_agg256(const f16* __restrict__ xh,
                                                const int* __restrict__ offs,
                                                const int* __restrict__ csr,
                                                const float* __restrict__ dinv,
                                                u16* __restrict__ ohi, u16* __restrict__ olo) {
  int wv = threadIdx.x >> 6, lane = threadIdx.x & 63;
  int v = blockIdx.x * 4 + wv;
  int f = lane << 2;
  int s = offs[v], t = offs[v + 1];
  float dv = dinv[v];
  float a0 = 0.f, a1 = 0.f, a2 = 0.f, a3 = 0.f;
  for (int j = s; j <= t; ++j) {
    int u = (j < t) ? csr[j] : v;
    float wg = (j < t) ? dinv[u] : dv;
    f16x4 hv = *(const f16x4*)(xh + (size_t)u * DIN + f);
    a0 += wg * (float)hv[0]; a1 += wg * (float)hv[1];
    a2 += wg * (float)hv[2]; a3 += wg * (float)hv[3];
  }
  a0 *= dv; a1 *= dv; a2 *= dv; a3 *= dv;
  u16 h0, l0, h1, l1, h2, l2, h3, l3;
  split2(a0, h0, l0); split2(a1, h1, l1); split2(a2, h2, l2); split2(a3, h3, l3);
  uint2 vh = {(unsigned)h0 | ((unsigned)h1 << 16), (unsigned)h2 | ((unsigned)h3 << 16)};
  uint2 vl = {(unsigned)l0 | ((unsigned)l1 << 16), (unsigned)l2 | ((unsigned)l3 << 16)};
  *(uint2*)(ohi + (size_t)v * DIN + f) = vh;
  *(uint2*)(olo + (size_t)v * DIN + f) = vl;
}

// ---------------- aggregation, 512-dim fp16 in -> +bias -> fp16 out ----------------
__global__ __launch_bounds__(256) void k_agg512(const f16* __restrict__ T2,
                                                const int* __restrict__ offs,
                                                const int* __restrict__ csr,
                                                const float* __restrict__ dinv,
                                                const float* __restrict__ bias,
                                                f16* __restrict__ H2) {
  int half = threadIdx.x >> 7, tid = threadIdx.x & 127;
  int v = blockIdx.x * 2 + half;
  int f = tid << 2;
  int s = offs[v], t = offs[v + 1];
  float dv = dinv[v];
  float a0 = 0.f, a1 = 0.f, a2 = 0.f, a3 = 0.f;
  for (int j = s; j <= t; ++j) {
    int u = (j < t) ? csr[j] : v;
    float wg = (j < t) ? dinv[u] : dv;
    f16x4 hv = *(const f16x4*)(T2 + (size_t)u * DH + f);
    a0 += wg * (float)hv[0]; a1 += wg * (float)hv[1];
    a2 += wg * (float)hv[2]; a3 += wg * (float)hv[3];
  }
  float4 bb = *(const float4*)(bias + f);
  f16x4 out = {(f16)(a0 * dv + bb.x), (f16)(a1 * dv + bb.y),
               (f16)(a2 * dv + bb.z), (f16)(a3 * dv + bb.w)};
  *(f16x4*)(H2 + (size_t)v * DH + f) = out;
}

// ---------------- LSTM elementwise (writes hs fp32 + split gates-input) ----------------
__global__ __launch_bounds__(256) void k_lstm(const float* __restrict__ gates,
                                              const float* __restrict__ b_ih,
                                              const float* __restrict__ b_hh,
                                              float* __restrict__ cs,
                                              float* __restrict__ hs,
                                              float* __restrict__ qstar,
                                              u16* __restrict__ qhhi, u16* __restrict__ qhlo) {
  int idx = blockIdx.x * 256 + threadIdx.x;
  int g = idx >> 9, j = idx & 511;
  const float* grow = gates + (size_t)g * 2048;
  float iv = grow[j]        + b_ih[j]        + b_hh[j];
  float fv = grow[512 + j]  + b_ih[512 + j]  + b_hh[512 + j];
  float gv = grow[1024 + j] + b_ih[1024 + j] + b_hh[1024 + j];
  float ov = grow[1536 + j] + b_ih[1536 + j] + b_hh[1536 + j];
  float si = 1.f / (1.f + expf(-iv));
  float sf = 1.f / (1.f + expf(-fv));
  float so = 1.f / (1.f + expf(-ov));
  float c = sf * cs[idx] + si * tanhf(gv);
  float h = so * tanhf(c);
  cs[idx] = c;
  hs[idx] = h;
  qstar[(size_t)g * 1024 + j] = h;
  u16 hh, hl;
  split2(h, hh, hl);
  size_t q = (size_t)g * 1536;
  qhhi[q + j] = hh;        qhlo[q + j] = hl;         // q_star cols 0..511 (= hs)
  qhhi[q + 1024 + j] = hh; qhlo[q + 1024 + j] = hl;  // W_hh input cols
}

// ---------------- fused attention-dot + per-graph softmax + pooling ----------------
__global__ __launch_bounds__(256) void k_pool(const f16* __restrict__ H2,
                                              const float* __restrict__ hs,
                                              const int* __restrict__ starts,
                                              float* __restrict__ qstar,
                                              u16* __restrict__ qhhi, u16* __restrict__ qhlo,
                                              float* __restrict__ spill) {
  int g = blockIdx.x;
  int s = starts[g], t = starts[g + 1];
  int cnt = t - s;
  int tid = threadIdx.x, wv = tid >> 6, lane = tid & 63;
  __shared__ float shs[512];
  __shared__ float se[1024];
  __shared__ float red[4];
  for (int i = tid; i < 512; i += 256) shs[i] = hs[(size_t)g * 512 + i];
  __syncthreads();
  bool big = cnt > 1024;
  // phase A: e[i] = dot(H2[s+i], hs[g]) — one wave per node
  for (int base = 0; base < cnt; base += 4) {
    int i = base + wv;
    if (i < cnt) {
      const f16* row = H2 + (size_t)(s + i) * DH;
      float acc = 0.f;
#pragma unroll
      for (int tt = 0; tt < 4; ++tt) {
        int c = (lane << 1) + (tt << 7);
        f16x2 hv = *(const f16x2*)(row + c);
        acc += (float)hv[0] * shs[c] + (float)hv[1] * shs[c + 1];
      }
#pragma unroll
      for (int o = 32; o > 0; o >>= 1) acc += __shfl_down(acc, o);
      if (lane == 0) { if (big) spill[s + i] = acc; else se[i] = acc; }
    }
  }
  __syncthreads();
  // max
  float m = -INFINITY;
  for (int i = tid; i < cnt; i += 256) m = fmaxf(m, big ? spill[s + i] : se[i]);
#pragma unroll
  for (int o = 32; o > 0; o >>= 1) m = fmaxf(m, __shfl_down(m, o));
  if (lane == 0) red[wv] = m;
  __syncthreads();
  m = fmaxf(fmaxf(red[0], red[1]), fmaxf(red[2], red[3]));
  if (!(m > -3.0e38f)) m = 0.f;
  __syncthreads();
  // sum exp
  float sm = 0.f;
  for (int i = tid; i < cnt; i += 256) sm += expf((big ? spill[s + i] : se[i]) - m);
#pragma unroll
  for (int o = 32; o > 0; o >>= 1) sm += __shfl_down(sm, o);
  if (lane == 0) red[wv] = sm;
  __syncthreads();
  float inv = 1.f / fmaxf(red[0] + red[1] + red[2] + red[3], 1e-12f);
  // normalize weights in place
  for (int i = tid; i < cnt; i += 256) {
    if (big) spill[s + i] = expf(spill[s + i] - m) * inv;
    else se[i] = expf(se[i] - m) * inv;
  }
  __syncthreads();
  // phase B: r[f] = sum_i a_i * H2[s+i][f]
  int f = tid << 1;
  float ax = 0.f, ay = 0.f;
  for (int i = 0; i < cnt; ++i) {
    float a = big ? spill[s + i] : se[i];
    f16x2 hv = *(const f16x2*)(H2 + (size_t)(s + i) * DH + f);
    ax += a * (float)hv[0];
    ay += a * (float)hv[1];
  }
  qstar[(size_t)g * 1024 + 512 + f] = ax;
  qstar[(size_t)g * 1024 + 513 + f] = ay;
  u16 hx, lx, hy, ly;
  split2(ax, hx, lx); split2(ay, hy, ly);
  size_t q = (size_t)g * 1536 + 512 + f;
  qhhi[q] = hx;     qhlo[q] = lx;
  qhhi[q + 1] = hy; qhlo[q + 1] = ly;
}

// ---------------- launch ----------------
extern "C" void kernel_launch(void* const* d_in, const int* in_sizes, int n_in,
                              void* d_out, int out_size, void* d_ws, size_t ws_size,
                              hipStream_t stream) {
  const float* x     = (const float*)d_in[0];
  const int*   ei    = (const int*)d_in[1];
  const int*   batch = (const int*)d_in[2];
  const float* W1    = (const float*)d_in[3];
  const float* b1    = (const float*)d_in[4];
  const float* W2    = (const float*)d_in[5];
  const float* b2    = (const float*)d_in[6];
  const float* W_ih  = (const float*)d_in[7];
  const float* W_hh  = (const float*)d_in[8];
  const float* b_ih  = (const float*)d_in[9];
  const float* b_hh  = (const float*)d_in[10];
  float* qstar = (float*)d_out;

  char* w = (char*)d_ws;
  size_t off = 0;
  auto carve = [&](size_t bytes) -> void* {
    void* p = w + off;
    off += (bytes + 255) & ~(size_t)255;
    return p;
  };
  f16* xh      = (f16*)carve((size_t)NN * DIN * 2);
  u16* axhi    = (u16*)carve((size_t)NN * DIN * 2);
  u16* axlo    = (u16*)carve((size_t)NN * DIN * 2);
  u16* h1hi    = (u16*)carve((size_t)NN * DH * 2);
  u16* h1lo    = (u16*)carve((size_t)NN * DH * 2);
  f16* t2h     = (f16*)carve((size_t)NN * DH * 2);
  f16* H2h     = (f16*)carve((size_t)NN * DH * 2);
  u16* w1thi   = (u16*)carve((size_t)DH * DIN * 2);
  u16* w1tlo   = (u16*)carve((size_t)DH * DIN * 2);
  u16* w2thi   = (u16*)carve((size_t)DH * DH * 2);
  u16* w2tlo   = (u16*)carve((size_t)DH * DH * 2);
  u16* wghi    = (u16*)carve((size_t)2048 * 1536 * 2);
  u16* wglo    = (u16*)carve((size_t)2048 * 1536 * 2);
  u16* qhhi    = (u16*)carve((size_t)NG * 1536 * 2);
  u16* qhlo    = (u16*)carve((size_t)NG * 1536 * 2);
  int* counts  = (int*)carve((size_t)NN * 4);
  int* offs    = (int*)carve((size_t)(NN + 1) * 4);
  int* cursor  = (int*)carve((size_t)NN * 4);
  int* csr     = (int*)carve((size_t)NE * 4);
  float* dinv  = (float*)carve((size_t)NN * 4);
  float* gates = (float*)carve((size_t)NG * 2048 * 4);
  float* hs    = (float*)carve((size_t)NG * DOUT * 4);
  float* cs    = (float*)carve((size_t)NG * DOUT * 4);
  float* spill = (float*)carve((size_t)NN * 4);
  int* starts  = (int*)carve((size_t)(NG + 1) * 4);

  hipMemsetAsync(counts, 0, (size_t)NN * 4, stream);
  hipMemsetAsync(cursor, 0, (size_t)NN * 4, stream);
  hipMemsetAsync(hs, 0, (size_t)NG * DOUT * 4, stream);
  hipMemsetAsync(cs, 0, (size_t)NG * DOUT * 4, stream);
  hipMemsetAsync(qstar, 0, (size_t)NG * 1024 * 4, stream);
  hipMemsetAsync(qhhi, 0, (size_t)NG * 1536 * 2, stream);
  hipMemsetAsync(qhlo, 0, (size_t)NG * 1536 * 2, stream);

  k_count<<<NE / 256, 256, 0, stream>>>(ei, counts);
  k_scan<<<1, 1024, 0, stream>>>(counts, offs);
  k_fill<<<NE / 256, 256, 0, stream>>>(ei, offs, cursor, csr);
  k_dinv<<<NN / 256, 256, 0, stream>>>(counts, dinv);
  k_starts<<<1, NG, 0, stream>>>(batch, starts);

  k_half<<<NN * DIN / 1024, 256, 0, stream>>>(x, xh);
  k_split_t<<<(DIN * DH + 255) / 256, 256, 0, stream>>>(W1, w1thi, w1tlo, DIN, DH, DIN * DH);
  k_split_t<<<(DH * DH + 255) / 256, 256, 0, stream>>>(W2, w2thi, w2tlo, DH, DH, DH * DH);
  k_split<<<(2048 * 1024 + 255) / 256, 256, 0, stream>>>(W_ih, wghi, wglo, 1024, 1536, 0, 2048 * 1024);
  k_split<<<(2048 * 512 + 255) / 256, 256, 0, stream>>>(W_hh, wghi, wglo, 512, 1536, 1024, 2048 * 512);

  // layer 1: aggx = Agg(x) ; H1 = relu(aggx@W1 + b1)
  k_agg256<<<NN / 4, 256, 0, stream>>>(xh, offs, csr, dinv, axhi, axlo);
  k_mfma_gemm<1><<<(NN / 128) * (DH / 128), 256, 0, stream>>>(
      axhi, axlo, w1thi, w1tlo, nullptr, h1hi, h1lo, nullptr, b1, NN, DH, DIN);
  // layer 2: t2 = H1@W2 ; H2 = Agg(t2) + b2
  k_mfma_gemm<2><<<(NN / 128) * (DH / 128), 256, 0, stream>>>(
      h1hi, h1lo, w2thi, w2tlo, nullptr, nullptr, nullptr, t2h, nullptr, NN, DH, DH);
  k_agg512<<<NN / 2, 256, 0, stream>>>(t2h, offs, csr, dinv, b2, H2h);

  for (int step = 0; step < 3; ++step) {
    k_mfma_gemm<0><<<(NG / 128) * (2048 / 128), 256, 0, stream>>>(
        qhhi, qhlo, wghi, wglo, gates, nullptr, nullptr, nullptr, nullptr, NG, 2048, 1536);
    k_lstm<<<(NG * DOUT) / 256, 256, 0, stream>>>(gates, b_ih, b_hh, cs, hs, qstar, qhhi, qhlo);
    k_pool<<<NG, 256, 0, stream>>>(H2h, hs, starts, qstar, qhhi, qhlo, spill);
  }
}

// Round 4
// 374.393 us; speedup vs baseline: 3.0812x; 1.4394x over previous
//
#include <hip/hip_runtime.h>
#include <math.h>

#define NN 32768
#define NE 262144
#define NG 256
#define DIN 256
#define DH 512
#define DOUT 512

typedef unsigned short u16;
typedef _Float16 f16;
typedef __attribute__((ext_vector_type(4))) _Float16 f16x4;
typedef __attribute__((ext_vector_type(8))) _Float16 f16x8;
typedef __attribute__((ext_vector_type(8))) short short8;
typedef __attribute__((ext_vector_type(4))) float f32x4;

__device__ inline u16 bf16rn(float f) {
  unsigned u = __float_as_uint(f);
  return (u16)((u + 0x7fff + ((u >> 16) & 1)) >> 16);
}
__device__ inline float bfbits(u16 b) { return __uint_as_float(((unsigned)b) << 16); }
__device__ inline void split2(float f, u16& h, u16& l) {
  h = bf16rn(f);
  float r = f - bfbits(h);
  l = bf16rn(r);
}

__device__ inline void gload16(const void* g, void* l) {
  __builtin_amdgcn_global_load_lds((const __attribute__((address_space(1))) unsigned int*)g,
                                   (__attribute__((address_space(3))) unsigned int*)l,
                                   16, 0, 0);
}

// ---------------- graph prep ----------------

__global__ void k_count(const int* __restrict__ ei, int* __restrict__ counts) {
  int e = blockIdx.x * 256 + threadIdx.x;
  if (e < NE) atomicAdd(&counts[ei[NE + e]], 1);
}

__global__ __launch_bounds__(1024) void k_scan(const int* __restrict__ counts,
                                               int* __restrict__ offs) {
  __shared__ int sums[1024];
  int tid = threadIdx.x;
  int base = tid * 32;
  int local[32];
  int s = 0;
#pragma unroll
  for (int i = 0; i < 32; ++i) { local[i] = counts[base + i]; s += local[i]; }
  sums[tid] = s;
  __syncthreads();
  for (int off = 1; off < 1024; off <<= 1) {
    int add = (tid >= off) ? sums[tid - off] : 0;
    __syncthreads();
    sums[tid] += add;
    __syncthreads();
  }
  int prefix = (tid == 0) ? 0 : sums[tid - 1];
#pragma unroll
  for (int i = 0; i < 32; ++i) { offs[base + i] = prefix; prefix += local[i]; }
  if (tid == 1023) offs[NN] = prefix;
}

__global__ void k_fill(const int* __restrict__ ei, const int* __restrict__ offs,
                       int* __restrict__ cursor, int* __restrict__ csr) {
  int e = blockIdx.x * 256 + threadIdx.x;
  if (e < NE) {
    int d = ei[NE + e];
    int pos = offs[d] + atomicAdd(&cursor[d], 1);
    csr[pos] = ei[e];
  }
}

__global__ void k_dinv(const int* __restrict__ counts, float* __restrict__ dinv) {
  int v = blockIdx.x * 256 + threadIdx.x;
  if (v < NN) dinv[v] = rsqrtf((float)(counts[v] + 1));
}

__global__ void k_starts(const int* __restrict__ batch, int* __restrict__ starts) {
  int g = threadIdx.x;
  int lo = 0, hi = NN;
  while (lo < hi) {
    int mid = (lo + hi) >> 1;
    if (batch[mid] < g) lo = mid + 1; else hi = mid;
  }
  starts[g] = lo;
  if (g == 0) starts[NG] = NN;
}

// ---------------- conversions / weight prep ----------------

__global__ void k_half(const float* __restrict__ src, f16* __restrict__ dst) {
  int i = (blockIdx.x * 256 + threadIdx.x) << 2;
  float4 v = *(const float4*)(src + i);
  f16x4 h = {(f16)v.x, (f16)v.y, (f16)v.z, (f16)v.w};
  *(f16x4*)(dst + i) = h;
}

// transpose split: src [K][N] fp32 -> dst [N][K] bf16 hi/lo
__global__ void k_split_t(const float* __restrict__ src, u16* __restrict__ hi, u16* __restrict__ lo,
                          int K, int N, int total) {
  int idx = blockIdx.x * 256 + threadIdx.x;
  if (idx >= total) return;
  int k = idx / N, n = idx - k * N;
  u16 h, l;
  split2(src[idx], h, l);
  size_t d = (size_t)n * K + k;
  hi[d] = h; lo[d] = l;
}

// combined gates weight: wg[n][c] = (c<512 ? W_ih[n][c]+W_hh[n][c] : W_ih[n][c]), split hi/lo
__global__ void k_wc(const float* __restrict__ W_ih, const float* __restrict__ W_hh,
                     u16* __restrict__ wghi, u16* __restrict__ wglo) {
  int idx = blockIdx.x * 256 + threadIdx.x;  // 2048*1024
  int n = idx >> 10, c = idx & 1023;
  float v = W_ih[(size_t)n * 1024 + c];
  if (c < 512) v += W_hh[(size_t)n * 512 + c];
  u16 h, l;
  split2(v, h, l);
  wghi[idx] = h; wglo[idx] = l;
}

// ---------------- split-bf16 MFMA GEMM ----------------
// C[M][N] = A[M][K'] @ Bt[N][K']^T over K elems starting at slice*K (split-K).
// MODE 0: fp32 C (partial, offset slice*M*N). MODE 1: +bias, relu, split->Chi/Clo. MODE 2: f16 out.
template <int MODE>
__global__ __launch_bounds__(256) void k_mfma_gemm(
    const u16* __restrict__ Ahi, const u16* __restrict__ Alo,
    const u16* __restrict__ Bhi, const u16* __restrict__ Blo,
    float* __restrict__ C, u16* __restrict__ Chi, u16* __restrict__ Clo,
    f16* __restrict__ Cf16, const float* __restrict__ bias,
    int M, int N, int K, int lda, int ldb) {
  __shared__ char lds[65536];

  int nbn = N >> 7;
  int nwg = (M >> 7) * nbn;
  int b = blockIdx.x;
  int slice = b / nwg;
  b -= slice * nwg;
  int koff = slice * K;
  int swz = (b & 7) * (nwg >> 3) + (b >> 3);  // nwg % 8 == 0 for all our shapes
  int bn = (swz % nbn) << 7;
  int bm = (swz / nbn) << 7;

  int tid = threadIdx.x;
  int w = tid >> 6, lane = tid & 63;
  int wm = (w >> 1) << 6, wn = (w & 1) << 6;
  int fr = lane & 15;
  int fq = lane >> 4;

  f32x4 acc[4][4];
#pragma unroll
  for (int i = 0; i < 4; ++i)
#pragma unroll
    for (int j = 0; j < 4; ++j) acc[i][j] = (f32x4){0.f, 0.f, 0.f, 0.f};

  for (int ks = 0; ks < K; ks += 64) {
#pragma unroll
    for (int i = 0; i < 4; ++i) {
      int L = i * 256 + tid;
      int row = L >> 3;
      int ke = ((L & 7) ^ (row & 7)) << 3;
      int ldsoff = i * 4096 + w * 1024;
      gload16(Ahi + (size_t)(bm + row) * lda + koff + ks + ke, lds + ldsoff);
      gload16(Alo + (size_t)(bm + row) * lda + koff + ks + ke, lds + 16384 + ldsoff);
      gload16(Bhi + (size_t)(bn + row) * ldb + koff + ks + ke, lds + 32768 + ldsoff);
      gload16(Blo + (size_t)(bn + row) * ldb + koff + ks + ke, lds + 49152 + ldsoff);
    }
    __syncthreads();
#pragma unroll
    for (int kk = 0; kk < 2; ++kk) {
      short8 ah[4], al[4], bh[4], bl[4];
#pragma unroll
      for (int m = 0; m < 4; ++m) {
        int row = wm + m * 16 + fr;
        int boff = row * 128 + (((kk << 6) + (fq << 4)) ^ ((row & 7) << 4));
        ah[m] = *(const short8*)(lds + boff);
        al[m] = *(const short8*)(lds + 16384 + boff);
      }
#pragma unroll
      for (int n = 0; n < 4; ++n) {
        int row = wn + n * 16 + fr;
        int boff = row * 128 + (((kk << 6) + (fq << 4)) ^ ((row & 7) << 4));
        bh[n] = *(const short8*)(lds + 32768 + boff);
        bl[n] = *(const short8*)(lds + 49152 + boff);
      }
#pragma unroll
      for (int m = 0; m < 4; ++m)
#pragma unroll
        for (int n = 0; n < 4; ++n) {
          acc[m][n] = __builtin_amdgcn_mfma_f32_16x16x32_bf16(ah[m], bh[n], acc[m][n], 0, 0, 0);
          acc[m][n] = __builtin_amdgcn_mfma_f32_16x16x32_bf16(ah[m], bl[n], acc[m][n], 0, 0, 0);
          acc[m][n] = __builtin_amdgcn_mfma_f32_16x16x32_bf16(al[m], bh[n], acc[m][n], 0, 0, 0);
        }
    }
    __syncthreads();
  }
#pragma unroll
  for (int m = 0; m < 4; ++m)
#pragma unroll
    for (int n = 0; n < 4; ++n)
#pragma unroll
      for (int i = 0; i < 4; ++i) {
        int r = bm + wm + m * 16 + fq * 4 + i;
        int c = bn + wn + n * 16 + fr;
        float val = acc[m][n][i];
        if (MODE == 1) {
          val += bias[c];
          val = fmaxf(val, 0.f);
          u16 h, l;
          split2(val, h, l);
          Chi[(size_t)r * N + c] = h;
          Clo[(size_t)r * N + c] = l;
        } else if (MODE == 2) {
          Cf16[(size_t)r * N + c] = (f16)val;
        } else {
          C[(size_t)slice * M * N + (size_t)r * N + c] = val;
        }
      }
}

// ---------------- aggregation, 256-dim fp16 -> bf16 hi/lo. One wave per node. ----------------
__global__ __launch_bounds__(256) void k_agg256(const f16* __restrict__ xh,
                                                const int* __restrict__ offs,
                                                const int* __restrict__ csr,
                                                const float* __restrict__ dinv,
                                                u16* __restrict__ ohi, u16* __restrict__ olo) {
  int wv = threadIdx.x >> 6, lane = threadIdx.x & 63;
  int v = blockIdx.x * 4 + wv;
  int f = lane << 2;
  int s = offs[v], t = offs[v + 1];
  float dv = dinv[v];
  float a0[4] = {0.f, 0.f, 0.f, 0.f}, a1[4] = {0.f, 0.f, 0.f, 0.f};
  for (int base = s; base < t; base += 64) {
    int rem = min(64, t - base);
    int idx = (lane < rem) ? csr[base + lane] : 0;
    float wl = (lane < rem) ? dinv[idx] : 0.f;
    int i = 0;
    for (; i + 1 < rem; i += 2) {
      int u0 = __shfl(idx, i), u1 = __shfl(idx, i + 1);
      float w0 = __shfl(wl, i), w1 = __shfl(wl, i + 1);
      f16x4 r0 = *(const f16x4*)(xh + (size_t)u0 * DIN + f);
      f16x4 r1 = *(const f16x4*)(xh + (size_t)u1 * DIN + f);
#pragma unroll
      for (int k = 0; k < 4; ++k) { a0[k] += w0 * (float)r0[k]; a1[k] += w1 * (float)r1[k]; }
    }
    if (i < rem) {
      int u0 = __shfl(idx, i);
      float w0 = __shfl(wl, i);
      f16x4 r0 = *(const f16x4*)(xh + (size_t)u0 * DIN + f);
#pragma unroll
      for (int k = 0; k < 4; ++k) a0[k] += w0 * (float)r0[k];
    }
  }
  f16x4 rs = *(const f16x4*)(xh + (size_t)v * DIN + f);
  u16 h[4], l[4];
#pragma unroll
  for (int k = 0; k < 4; ++k) {
    float r = (a0[k] + a1[k] + dv * (float)rs[k]) * dv;
    split2(r, h[k], l[k]);
  }
  uint2 vh = {(unsigned)h[0] | ((unsigned)h[1] << 16), (unsigned)h[2] | ((unsigned)h[3] << 16)};
  uint2 vl = {(unsigned)l[0] | ((unsigned)l[1] << 16), (unsigned)l[2] | ((unsigned)l[3] << 16)};
  *(uint2*)(ohi + (size_t)v * DIN + f) = vh;
  *(uint2*)(olo + (size_t)v * DIN + f) = vl;
}

// ---------------- aggregation, 512-dim fp16 + bias -> fp16. One wave per node. ----------------
__global__ __launch_bounds__(256) void k_agg512(const f16* __restrict__ T2,
                                                const int* __restrict__ offs,
                                                const int* __restrict__ csr,
                                                const float* __restrict__ dinv,
                                                const float* __restrict__ bias,
                                                f16* __restrict__ H2) {
  int wv = threadIdx.x >> 6, lane = threadIdx.x & 63;
  int v = blockIdx.x * 4 + wv;
  int f = lane << 3;
  int s = offs[v], t = offs[v + 1];
  float dv = dinv[v];
  float a0[8] = {}, a1[8] = {};
  for (int base = s; base < t; base += 64) {
    int rem = min(64, t - base);
    int idx = (lane < rem) ? csr[base + lane] : 0;
    float wl = (lane < rem) ? dinv[idx] : 0.f;
    int i = 0;
    for (; i + 1 < rem; i += 2) {
      int u0 = __shfl(idx, i), u1 = __shfl(idx, i + 1);
      float w0 = __shfl(wl, i), w1 = __shfl(wl, i + 1);
      f16x8 r0 = *(const f16x8*)(T2 + (size_t)u0 * DH + f);
      f16x8 r1 = *(const f16x8*)(T2 + (size_t)u1 * DH + f);
#pragma unroll
      for (int k = 0; k < 8; ++k) { a0[k] += w0 * (float)r0[k]; a1[k] += w1 * (float)r1[k]; }
    }
    if (i < rem) {
      int u0 = __shfl(idx, i);
      float w0 = __shfl(wl, i);
      f16x8 r0 = *(const f16x8*)(T2 + (size_t)u0 * DH + f);
#pragma unroll
      for (int k = 0; k < 8; ++k) a0[k] += w0 * (float)r0[k];
    }
  }
  f16x8 rs = *(const f16x8*)(T2 + (size_t)v * DH + f);
  float4 bb0 = *(const float4*)(bias + f);
  float4 bb1 = *(const float4*)(bias + f + 4);
  float bbv[8] = {bb0.x, bb0.y, bb0.z, bb0.w, bb1.x, bb1.y, bb1.z, bb1.w};
  f16x8 out;
#pragma unroll
  for (int k = 0; k < 8; ++k)
    out[k] = (f16)((a0[k] + a1[k] + dv * (float)rs[k]) * dv + bbv[k]);
  *(f16x8*)(H2 + (size_t)v * DH + f) = out;
}

// ---------------- LSTM elementwise (sums split-K partials; writes hs + gates-GEMM A) ----------------
__global__ __launch_bounds__(256) void k_lstm(const float* __restrict__ gp,
                                              const float* __restrict__ b_ih,
                                              const float* __restrict__ b_hh,
                                              float* __restrict__ cs,
                                              float* __restrict__ hs,
                                              float* __restrict__ qstar,
                                              u16* __restrict__ qhhi, u16* __restrict__ qhlo) {
  int idx = blockIdx.x * 256 + threadIdx.x;
  int g = idx >> 9, j = idx & 511;
  const float* g0 = gp + (size_t)g * 2048;
  const float* g1 = gp + 524288 + (size_t)g * 2048;
  float iv = g0[j]        + g1[j]        + b_ih[j]        + b_hh[j];
  float fv = g0[512 + j]  + g1[512 + j]  + b_ih[512 + j]  + b_hh[512 + j];
  float gv = g0[1024 + j] + g1[1024 + j] + b_ih[1024 + j] + b_hh[1024 + j];
  float ov = g0[1536 + j] + g1[1536 + j] + b_ih[1536 + j] + b_hh[1536 + j];
  float si = 1.f / (1.f + expf(-iv));
  float sf = 1.f / (1.f + expf(-fv));
  float so = 1.f / (1.f + expf(-ov));
  float c = sf * cs[idx] + si * tanhf(gv);
  float h = so * tanhf(c);
  cs[idx] = c;
  hs[idx] = h;
  qstar[(size_t)g * 1024 + j] = h;
  u16 hh, hl;
  split2(h, hh, hl);
  qhhi[(size_t)g * 1024 + j] = hh;
  qhlo[(size_t)g * 1024 + j] = hl;
}

// ---------------- fused flash-style dot + softmax + pooling (single H2 pass) ----------------
__global__ __launch_bounds__(256) void k_pool(const f16* __restrict__ H2,
                                              const float* __restrict__ hs,
                                              const int* __restrict__ starts,
                                              float* __restrict__ qstar,
                                              u16* __restrict__ qhhi, u16* __restrict__ qhlo) {
  int g = blockIdx.x;
  int s = starts[g], t = starts[g + 1];
  int cnt = t - s;
  int tid = threadIdx.x, wv = tid >> 6, lane = tid & 63;
  __shared__ float lm[4], ls[4];
  __shared__ float lr[4][512];

  float hsr[8];
  {
    float4 q0 = *(const float4*)(hs + (size_t)g * 512 + lane * 8);
    float4 q1 = *(const float4*)(hs + (size_t)g * 512 + lane * 8 + 4);
    hsr[0] = q0.x; hsr[1] = q0.y; hsr[2] = q0.z; hsr[3] = q0.w;
    hsr[4] = q1.x; hsr[5] = q1.y; hsr[6] = q1.z; hsr[7] = q1.w;
  }
  float m = -INFINITY, ssum = 0.f;
  float racc[8] = {};
  for (int i = wv; i < cnt; i += 4) {
    f16x8 rv = *(const f16x8*)(H2 + (size_t)(s + i) * DH + lane * 8);
    float e = 0.f;
#pragma unroll
    for (int k = 0; k < 8; ++k) e += (float)rv[k] * hsr[k];
#pragma unroll
    for (int o = 1; o < 64; o <<= 1) e += __shfl_xor(e, o);
    float mn = fmaxf(m, e);
    float scale = expf(m - mn);   // first iter: exp(-inf)=0
    float p = expf(e - mn);
    ssum = ssum * scale + p;
#pragma unroll
    for (int k = 0; k < 8; ++k) racc[k] = racc[k] * scale + p * (float)rv[k];
    m = mn;
  }
  if (lane == 0) { lm[wv] = m; ls[wv] = ssum; }
#pragma unroll
  for (int k = 0; k < 8; ++k) lr[wv][lane * 8 + k] = racc[k];
  __syncthreads();
  float M = fmaxf(fmaxf(lm[0], lm[1]), fmaxf(lm[2], lm[3]));
  if (!(M > -3.0e38f)) M = 0.f;  // empty graph
  float sc0 = expf(lm[0] - M), sc1 = expf(lm[1] - M);
  float sc2 = expf(lm[2] - M), sc3 = expf(lm[3] - M);
  float denom = ls[0] * sc0 + ls[1] * sc1 + ls[2] * sc2 + ls[3] * sc3;
  float inv = 1.f / fmaxf(denom, 1e-12f);
  int f = tid << 1;
  float r0 = (lr[0][f] * sc0 + lr[1][f] * sc1 + lr[2][f] * sc2 + lr[3][f] * sc3) * inv;
  float r1 = (lr[0][f + 1] * sc0 + lr[1][f + 1] * sc1 + lr[2][f + 1] * sc2 + lr[3][f + 1] * sc3) * inv;
  qstar[(size_t)g * 1024 + 512 + f] = r0;
  qstar[(size_t)g * 1024 + 513 + f] = r1;
  u16 h0, l0, h1, l1;
  split2(r0, h0, l0); split2(r1, h1, l1);
  size_t q = (size_t)g * 1024 + 512 + f;
  qhhi[q] = h0;     qhlo[q] = l0;
  qhhi[q + 1] = h1; qhlo[q + 1] = l1;
}

// ---------------- launch ----------------
extern "C" void kernel_launch(void* const* d_in, const int* in_sizes, int n_in,
                              void* d_out, int out_size, void* d_ws, size_t ws_size,
                              hipStream_t stream) {
  const float* x     = (const float*)d_in[0];
  const int*   ei    = (const int*)d_in[1];
  const int*   batch = (const int*)d_in[2];
  const float* W1    = (const float*)d_in[3];
  const float* b1    = (const float*)d_in[4];
  const float* W2    = (const float*)d_in[5];
  const float* b2    = (const float*)d_in[6];
  const float* W_ih  = (const float*)d_in[7];
  const float* W_hh  = (const float*)d_in[8];
  const float* b_ih  = (const float*)d_in[9];
  const float* b_hh  = (const float*)d_in[10];
  float* qstar = (float*)d_out;

  char* w = (char*)d_ws;
  size_t off = 0;
  auto carve = [&](size_t bytes) -> void* {
    void* p = w + off;
    off += (bytes + 255) & ~(size_t)255;
    return p;
  };
  f16* xh      = (f16*)carve((size_t)NN * DIN * 2);
  u16* axhi    = (u16*)carve((size_t)NN * DIN * 2);
  u16* axlo    = (u16*)carve((size_t)NN * DIN * 2);
  u16* h1hi    = (u16*)carve((size_t)NN * DH * 2);
  u16* h1lo    = (u16*)carve((size_t)NN * DH * 2);
  f16* t2h     = (f16*)carve((size_t)NN * DH * 2);
  f16* H2h     = (f16*)carve((size_t)NN * DH * 2);
  u16* w1thi   = (u16*)carve((size_t)DH * DIN * 2);
  u16* w1tlo   = (u16*)carve((size_t)DH * DIN * 2);
  u16* w2thi   = (u16*)carve((size_t)DH * DH * 2);
  u16* w2tlo   = (u16*)carve((size_t)DH * DH * 2);
  u16* wghi    = (u16*)carve((size_t)2048 * 1024 * 2);
  u16* wglo    = (u16*)carve((size_t)2048 * 1024 * 2);
  u16* qhhi    = (u16*)carve((size_t)NG * 1024 * 2);
  u16* qhlo    = (u16*)carve((size_t)NG * 1024 * 2);
  float* gp    = (float*)carve((size_t)2 * NG * 2048 * 4);
  int* counts  = (int*)carve((size_t)NN * 4);
  int* offs    = (int*)carve((size_t)(NN + 1) * 4);
  int* cursor  = (int*)carve((size_t)NN * 4);
  int* csr     = (int*)carve((size_t)NE * 4);
  float* dinv  = (float*)carve((size_t)NN * 4);
  float* hs    = (float*)carve((size_t)NG * DOUT * 4);
  float* cs    = (float*)carve((size_t)NG * DOUT * 4);
  int* starts  = (int*)carve((size_t)(NG + 1) * 4);

  hipMemsetAsync(counts, 0, (size_t)NN * 4, stream);
  hipMemsetAsync(cursor, 0, (size_t)NN * 4, stream);
  hipMemsetAsync(hs, 0, (size_t)NG * DOUT * 4, stream);
  hipMemsetAsync(cs, 0, (size_t)NG * DOUT * 4, stream);
  hipMemsetAsync(qstar, 0, (size_t)NG * 1024 * 4, stream);
  hipMemsetAsync(qhhi, 0, (size_t)NG * 1024 * 2, stream);
  hipMemsetAsync(qhlo, 0, (size_t)NG * 1024 * 2, stream);

  k_count<<<NE / 256, 256, 0, stream>>>(ei, counts);
  k_scan<<<1, 1024, 0, stream>>>(counts, offs);
  k_fill<<<NE / 256, 256, 0, stream>>>(ei, offs, cursor, csr);
  k_dinv<<<NN / 256, 256, 0, stream>>>(counts, dinv);
  k_starts<<<1, NG, 0, stream>>>(batch, starts);

  k_half<<<NN * DIN / 1024, 256, 0, stream>>>(x, xh);
  k_split_t<<<(DIN * DH + 255) / 256, 256, 0, stream>>>(W1, w1thi, w1tlo, DIN, DH, DIN * DH);
  k_split_t<<<(DH * DH + 255) / 256, 256, 0, stream>>>(W2, w2thi, w2tlo, DH, DH, DH * DH);
  k_wc<<<(2048 * 1024) / 256, 256, 0, stream>>>(W_ih, W_hh, wghi, wglo);

  // layer 1: aggx = Agg(x) ; H1 = relu(aggx@W1 + b1)
  k_agg256<<<NN / 4, 256, 0, stream>>>(xh, offs, csr, dinv, axhi, axlo);
  k_mfma_gemm<1><<<(NN / 128) * (DH / 128), 256, 0, stream>>>(
      axhi, axlo, w1thi, w1tlo, nullptr, h1hi, h1lo, nullptr, b1, NN, DH, DIN, DIN, DIN);
  // layer 2: t2 = H1@W2 ; H2 = Agg(t2) + b2
  k_mfma_gemm<2><<<(NN / 128) * (DH / 128), 256, 0, stream>>>(
      h1hi, h1lo, w2thi, w2tlo, nullptr, nullptr, nullptr, t2h, nullptr, NN, DH, DH, DH, DH);
  k_agg512<<<NN / 4, 256, 0, stream>>>(t2h, offs, csr, dinv, b2, H2h);

  for (int step = 0; step < 3; ++step) {
    // gates partials: 2 K-slices of 512 in one dispatch (grid 64)
    k_mfma_gemm<0><<<2 * (NG / 128) * (2048 / 128), 256, 0, stream>>>(
        qhhi, qhlo, wghi, wglo, gp, nullptr, nullptr, nullptr, nullptr,
        NG, 2048, 512, 1024, 1024);
    k_lstm<<<(NG * DOUT) / 256, 256, 0, stream>>>(gp, b_ih, b_hh, cs, hs, qstar, qhhi, qhlo);
    k_pool<<<NG, 256, 0, stream>>>(H2h, hs, starts, qstar, qhhi, qhlo);
  }
}

// Round 5
// 362.678 us; speedup vs baseline: 3.1807x; 1.0323x over previous
//
#include <hip/hip_runtime.h>
#include <math.h>

#define NN 32768
#define NE 262144
#define NG 256
#define DIN 256
#define DH 512
#define DOUT 512

typedef unsigned short u16;
typedef _Float16 f16;
typedef __attribute__((ext_vector_type(4))) _Float16 f16x4;
typedef __attribute__((ext_vector_type(8))) _Float16 f16x8;
typedef __attribute__((ext_vector_type(8))) short short8;
typedef __attribute__((ext_vector_type(4))) float f32x4;

__device__ inline u16 bf16rn(float f) {
  unsigned u = __float_as_uint(f);
  return (u16)((u + 0x7fff + ((u >> 16) & 1)) >> 16);
}
__device__ inline float bfbits(u16 b) { return __uint_as_float(((unsigned)b) << 16); }
__device__ inline void split2(float f, u16& h, u16& l) {
  h = bf16rn(f);
  float r = f - bfbits(h);
  l = bf16rn(r);
}

__device__ inline void gload16(const void* g, void* l) {
  __builtin_amdgcn_global_load_lds((const __attribute__((address_space(1))) unsigned int*)g,
                                   (__attribute__((address_space(3))) unsigned int*)l,
                                   16, 0, 0);
}

// ---------------- graph prep ----------------

__global__ void k_count(const int* __restrict__ ei, int* __restrict__ counts) {
  int e = blockIdx.x * 256 + threadIdx.x;
  if (e < NE) atomicAdd(&counts[ei[NE + e]], 1);
}

__global__ __launch_bounds__(1024) void k_scan(const int* __restrict__ counts,
                                               int* __restrict__ offs) {
  __shared__ int sums[1024];
  int tid = threadIdx.x;
  int base = tid * 32;
  int local[32];
  int s = 0;
#pragma unroll
  for (int i = 0; i < 32; ++i) { local[i] = counts[base + i]; s += local[i]; }
  sums[tid] = s;
  __syncthreads();
  for (int off = 1; off < 1024; off <<= 1) {
    int add = (tid >= off) ? sums[tid - off] : 0;
    __syncthreads();
    sums[tid] += add;
    __syncthreads();
  }
  int prefix = (tid == 0) ? 0 : sums[tid - 1];
#pragma unroll
  for (int i = 0; i < 32; ++i) { offs[base + i] = prefix; prefix += local[i]; }
  if (tid == 1023) offs[NN] = prefix;
}

__global__ void k_fill(const int* __restrict__ ei, const int* __restrict__ offs,
                       int* __restrict__ cursor, int* __restrict__ csr) {
  int e = blockIdx.x * 256 + threadIdx.x;
  if (e < NE) {
    int d = ei[NE + e];
    int pos = offs[d] + atomicAdd(&cursor[d], 1);
    csr[pos] = ei[e];
  }
}

__global__ void k_dinv(const int* __restrict__ counts, float* __restrict__ dinv) {
  int v = blockIdx.x * 256 + threadIdx.x;
  if (v < NN) dinv[v] = rsqrtf((float)(counts[v] + 1));
}

__global__ void k_starts(const int* __restrict__ batch, int* __restrict__ starts) {
  int g = threadIdx.x;
  int lo = 0, hi = NN;
  while (lo < hi) {
    int mid = (lo + hi) >> 1;
    if (batch[mid] < g) lo = mid + 1; else hi = mid;
  }
  starts[g] = lo;
  if (g == 0) starts[NG] = NN;
}

// ---------------- conversions / weight prep ----------------

__global__ void k_half(const float* __restrict__ src, f16* __restrict__ dst) {
  int i = (blockIdx.x * 256 + threadIdx.x) << 2;
  float4 v = *(const float4*)(src + i);
  f16x4 h = {(f16)v.x, (f16)v.y, (f16)v.z, (f16)v.w};
  *(f16x4*)(dst + i) = h;
}

// transpose split: src [K][N] fp32 -> dst [N][K] bf16 hi/lo
__global__ void k_split_t(const float* __restrict__ src, u16* __restrict__ hi, u16* __restrict__ lo,
                          int K, int N, int total) {
  int idx = blockIdx.x * 256 + threadIdx.x;
  if (idx >= total) return;
  int k = idx / N, n = idx - k * N;
  u16 h, l;
  split2(src[idx], h, l);
  size_t d = (size_t)n * K + k;
  hi[d] = h; lo[d] = l;
}

// combined gates weight: wg[n][c] = (c<512 ? W_ih[n][c]+W_hh[n][c] : W_ih[n][c]), split hi/lo
__global__ void k_wc(const float* __restrict__ W_ih, const float* __restrict__ W_hh,
                     u16* __restrict__ wghi, u16* __restrict__ wglo) {
  int idx = blockIdx.x * 256 + threadIdx.x;  // 2048*1024
  int n = idx >> 10, c = idx & 1023;
  float v = W_ih[(size_t)n * 1024 + c];
  if (c < 512) v += W_hh[(size_t)n * 512 + c];
  u16 h, l;
  split2(v, h, l);
  wghi[idx] = h; wglo[idx] = l;
}

// ---------------- split-bf16 MFMA GEMM, 2-phase double-buffered ----------------
// C[M][N] = A[M][K'] @ Bt[N][K']^T over K elems at koff = slice*K (split-K).
// 128x128 tile, BK=32, dbuf 2x32KB, one barrier per K-step (T3-min schedule).
// LDS row = 64B (32 bf16); swizzle: 16B slot ^= (row>>1)&3  -> 2 lanes/bank (free).
// MODE 0: fp32 C partial at slice*M*N. MODE 1: +bias, relu, split->Chi/Clo. MODE 2: f16 out.
template <int MODE>
__global__ __launch_bounds__(256) void k_mfma_gemm(
    const u16* __restrict__ Ahi, const u16* __restrict__ Alo,
    const u16* __restrict__ Bhi, const u16* __restrict__ Blo,
    float* __restrict__ C, u16* __restrict__ Chi, u16* __restrict__ Clo,
    f16* __restrict__ Cf16, const float* __restrict__ bias,
    int M, int N, int K, int lda, int ldb) {
  __shared__ char lds[65536];  // 2 bufs x (Ahi 8K | Alo 8K | Bhi 8K | Blo 8K)

  int nbn = N >> 7;
  int nwg = (M >> 7) * nbn;
  int b = blockIdx.x;
  int slice = b / nwg;
  b -= slice * nwg;
  int koff = slice * K;
  int swz = (b & 7) * (nwg >> 3) + (b >> 3);  // nwg % 8 == 0 for all our shapes
  int bn = (swz % nbn) << 7;
  int bm = (swz / nbn) << 7;

  int tid = threadIdx.x;
  int w = tid >> 6, lane = tid & 63;
  int wm = (w >> 1) << 6, wn = (w & 1) << 6;
  int fr = lane & 15;
  int fq = lane >> 4;

  f32x4 acc[4][4];
#pragma unroll
  for (int i = 0; i < 4; ++i)
#pragma unroll
    for (int j = 0; j < 4; ++j) acc[i][j] = (f32x4){0.f, 0.f, 0.f, 0.f};

  auto STAGE = [&](int buf, int ks) {
#pragma unroll
    for (int i = 0; i < 2; ++i) {
      int L = i * 256 + tid;
      int row = L >> 2;                          // 0..127
      int ke = ((L & 3) ^ ((row >> 1) & 3)) << 3; // logical k-elem start (pre-swizzled src)
      int ldsoff = buf * 32768 + i * 4096 + w * 1024;  // wave-uniform; +lane*16 by HW
      gload16(Ahi + (size_t)(bm + row) * lda + koff + ks + ke, lds + ldsoff);
      gload16(Alo + (size_t)(bm + row) * lda + koff + ks + ke, lds + 8192 + ldsoff);
      gload16(Bhi + (size_t)(bn + row) * ldb + koff + ks + ke, lds + 16384 + ldsoff);
      gload16(Blo + (size_t)(bn + row) * ldb + koff + ks + ke, lds + 24576 + ldsoff);
    }
  };

  int nt = K >> 5;
  STAGE(0, 0);
  __syncthreads();   // vmcnt(0) drain + barrier
  int cur = 0;
  for (int t = 0; t < nt; ++t) {
    if (t + 1 < nt) STAGE(cur ^ 1, (t + 1) << 5);   // issue next tile early
    const char* base = lds + cur * 32768;
    short8 ah[4], al[4], bh[4], bl[4];
#pragma unroll
    for (int m = 0; m < 4; ++m) {
      int row = wm + m * 16 + fr;
      int boff = row * 64 + ((fq ^ ((row >> 1) & 3)) << 4);
      ah[m] = *(const short8*)(base + boff);
      al[m] = *(const short8*)(base + 8192 + boff);
    }
#pragma unroll
    for (int n = 0; n < 4; ++n) {
      int row = wn + n * 16 + fr;
      int boff = row * 64 + ((fq ^ ((row >> 1) & 3)) << 4);
      bh[n] = *(const short8*)(base + 16384 + boff);
      bl[n] = *(const short8*)(base + 24576 + boff);
    }
#pragma unroll
    for (int m = 0; m < 4; ++m)
#pragma unroll
      for (int n = 0; n < 4; ++n) {
        acc[m][n] = __builtin_amdgcn_mfma_f32_16x16x32_bf16(ah[m], bh[n], acc[m][n], 0, 0, 0);
        acc[m][n] = __builtin_amdgcn_mfma_f32_16x16x32_bf16(ah[m], bl[n], acc[m][n], 0, 0, 0);
        acc[m][n] = __builtin_amdgcn_mfma_f32_16x16x32_bf16(al[m], bh[n], acc[m][n], 0, 0, 0);
      }
    __syncthreads();   // stage(t+1) landed; all reads of buf[cur] done
    cur ^= 1;
  }
#pragma unroll
  for (int m = 0; m < 4; ++m)
#pragma unroll
    for (int n = 0; n < 4; ++n)
#pragma unroll
      for (int i = 0; i < 4; ++i) {
        int r = bm + wm + m * 16 + fq * 4 + i;
        int c = bn + wn + n * 16 + fr;
        float val = acc[m][n][i];
        if (MODE == 1) {
          val += bias[c];
          val = fmaxf(val, 0.f);
          u16 h, l;
          split2(val, h, l);
          Chi[(size_t)r * N + c] = h;
          Clo[(size_t)r * N + c] = l;
        } else if (MODE == 2) {
          Cf16[(size_t)r * N + c] = (f16)val;
        } else {
          C[(size_t)slice * M * N + (size_t)r * N + c] = val;
        }
      }
}

// ---------------- aggregation, 256-dim fp16 -> bf16 hi/lo. One wave per node, ILP-4. ----------------
__global__ __launch_bounds__(256) void k_agg256(const f16* __restrict__ xh,
                                                const int* __restrict__ offs,
                                                const int* __restrict__ csr,
                                                const float* __restrict__ dinv,
                                                u16* __restrict__ ohi, u16* __restrict__ olo) {
  int wv = threadIdx.x >> 6, lane = threadIdx.x & 63;
  int v = blockIdx.x * 4 + wv;
  int f = lane << 2;
  int s = offs[v], t = offs[v + 1];
  float dv = dinv[v];
  float a0[4] = {}, a1[4] = {}, a2[4] = {}, a3[4] = {};
  for (int base = s; base < t; base += 64) {
    int rem = min(64, t - base);
    int idx = (lane < rem) ? csr[base + lane] : 0;
    float wl = (lane < rem) ? dinv[idx] : 0.f;
    int i = 0;
    for (; i + 3 < rem; i += 4) {
      int u0 = __shfl(idx, i), u1 = __shfl(idx, i + 1);
      int u2 = __shfl(idx, i + 2), u3 = __shfl(idx, i + 3);
      float w0 = __shfl(wl, i), w1 = __shfl(wl, i + 1);
      float w2 = __shfl(wl, i + 2), w3 = __shfl(wl, i + 3);
      f16x4 r0 = *(const f16x4*)(xh + (size_t)u0 * DIN + f);
      f16x4 r1 = *(const f16x4*)(xh + (size_t)u1 * DIN + f);
      f16x4 r2 = *(const f16x4*)(xh + (size_t)u2 * DIN + f);
      f16x4 r3 = *(const f16x4*)(xh + (size_t)u3 * DIN + f);
#pragma unroll
      for (int k = 0; k < 4; ++k) {
        a0[k] += w0 * (float)r0[k]; a1[k] += w1 * (float)r1[k];
        a2[k] += w2 * (float)r2[k]; a3[k] += w3 * (float)r3[k];
      }
    }
    for (; i < rem; ++i) {
      int u0 = __shfl(idx, i);
      float w0 = __shfl(wl, i);
      f16x4 r0 = *(const f16x4*)(xh + (size_t)u0 * DIN + f);
#pragma unroll
      for (int k = 0; k < 4; ++k) a0[k] += w0 * (float)r0[k];
    }
  }
  f16x4 rs = *(const f16x4*)(xh + (size_t)v * DIN + f);
  u16 h[4], l[4];
#pragma unroll
  for (int k = 0; k < 4; ++k) {
    float r = (a0[k] + a1[k] + a2[k] + a3[k] + dv * (float)rs[k]) * dv;
    split2(r, h[k], l[k]);
  }
  uint2 vh = {(unsigned)h[0] | ((unsigned)h[1] << 16), (unsigned)h[2] | ((unsigned)h[3] << 16)};
  uint2 vl = {(unsigned)l[0] | ((unsigned)l[1] << 16), (unsigned)l[2] | ((unsigned)l[3] << 16)};
  *(uint2*)(ohi + (size_t)v * DIN + f) = vh;
  *(uint2*)(olo + (size_t)v * DIN + f) = vl;
}

// ---------------- aggregation, 512-dim fp16 + bias -> fp16. One wave per node, ILP-4. ----------------
__global__ __launch_bounds__(256) void k_agg512(const f16* __restrict__ T2,
                                                const int* __restrict__ offs,
                                                const int* __restrict__ csr,
                                                const float* __restrict__ dinv,
                                                const float* __restrict__ bias,
                                                f16* __restrict__ H2) {
  int wv = threadIdx.x >> 6, lane = threadIdx.x & 63;
  int v = blockIdx.x * 4 + wv;
  int f = lane << 3;
  int s = offs[v], t = offs[v + 1];
  float dv = dinv[v];
  float a0[8] = {}, a1[8] = {}, a2[8] = {}, a3[8] = {};
  for (int base = s; base < t; base += 64) {
    int rem = min(64, t - base);
    int idx = (lane < rem) ? csr[base + lane] : 0;
    float wl = (lane < rem) ? dinv[idx] : 0.f;
    int i = 0;
    for (; i + 3 < rem; i += 4) {
      int u0 = __shfl(idx, i), u1 = __shfl(idx, i + 1);
      int u2 = __shfl(idx, i + 2), u3 = __shfl(idx, i + 3);
      float w0 = __shfl(wl, i), w1 = __shfl(wl, i + 1);
      float w2 = __shfl(wl, i + 2), w3 = __shfl(wl, i + 3);
      f16x8 r0 = *(const f16x8*)(T2 + (size_t)u0 * DH + f);
      f16x8 r1 = *(const f16x8*)(T2 + (size_t)u1 * DH + f);
      f16x8 r2 = *(const f16x8*)(T2 + (size_t)u2 * DH + f);
      f16x8 r3 = *(const f16x8*)(T2 + (size_t)u3 * DH + f);
#pragma unroll
      for (int k = 0; k < 8; ++k) {
        a0[k] += w0 * (float)r0[k]; a1[k] += w1 * (float)r1[k];
        a2[k] += w2 * (float)r2[k]; a3[k] += w3 * (float)r3[k];
      }
    }
    for (; i < rem; ++i) {
      int u0 = __shfl(idx, i);
      float w0 = __shfl(wl, i);
      f16x8 r0 = *(const f16x8*)(T2 + (size_t)u0 * DH + f);
#pragma unroll
      for (int k = 0; k < 8; ++k) a0[k] += w0 * (float)r0[k];
    }
  }
  f16x8 rs = *(const f16x8*)(T2 + (size_t)v * DH + f);
  float4 bb0 = *(const float4*)(bias + f);
  float4 bb1 = *(const float4*)(bias + f + 4);
  float bbv[8] = {bb0.x, bb0.y, bb0.z, bb0.w, bb1.x, bb1.y, bb1.z, bb1.w};
  f16x8 out;
#pragma unroll
  for (int k = 0; k < 8; ++k)
    out[k] = (f16)((a0[k] + a1[k] + a2[k] + a3[k] + dv * (float)rs[k]) * dv + bbv[k]);
  *(f16x8*)(H2 + (size_t)v * DH + f) = out;
}

// ---------------- LSTM elementwise (sums 4 split-K partials; writes hs + gates-GEMM A) ----------------
__global__ __launch_bounds__(256) void k_lstm(const float* __restrict__ gp,
                                              const float* __restrict__ b_ih,
                                              const float* __restrict__ b_hh,
                                              float* __restrict__ cs,
                                              float* __restrict__ hs,
                                              float* __restrict__ qstar,
                                              u16* __restrict__ qhhi, u16* __restrict__ qhlo) {
  int idx = blockIdx.x * 256 + threadIdx.x;
  int g = idx >> 9, j = idx & 511;
  const float* g0 = gp + (size_t)g * 2048;
  const float* g1 = g0 + 524288;
  const float* g2 = g0 + 1048576;
  const float* g3 = g0 + 1572864;
  float iv = g0[j]        + g1[j]        + g2[j]        + g3[j]        + b_ih[j]        + b_hh[j];
  float fv = g0[512 + j]  + g1[512 + j]  + g2[512 + j]  + g3[512 + j]  + b_ih[512 + j]  + b_hh[512 + j];
  float gv = g0[1024 + j] + g1[1024 + j] + g2[1024 + j] + g3[1024 + j] + b_ih[1024 + j] + b_hh[1024 + j];
  float ov = g0[1536 + j] + g1[1536 + j] + g2[1536 + j] + g3[1536 + j] + b_ih[1536 + j] + b_hh[1536 + j];
  float si = 1.f / (1.f + expf(-iv));
  float sf = 1.f / (1.f + expf(-fv));
  float so = 1.f / (1.f + expf(-ov));
  float c = sf * cs[idx] + si * tanhf(gv);
  float h = so * tanhf(c);
  cs[idx] = c;
  hs[idx] = h;
  qstar[(size_t)g * 1024 + j] = h;
  u16 hh, hl;
  split2(h, hh, hl);
  qhhi[(size_t)g * 1024 + j] = hh;
  qhlo[(size_t)g * 1024 + j] = hl;
}

// ---------------- fused flash-style dot + softmax + pooling (single H2 pass) ----------------
__global__ __launch_bounds__(256) void k_pool(const f16* __restrict__ H2,
                                              const float* __restrict__ hs,
                                              const int* __restrict__ starts,
                                              float* __restrict__ qstar,
                                              u16* __restrict__ qhhi, u16* __restrict__ qhlo) {
  int g = blockIdx.x;
  int s = starts[g], t = starts[g + 1];
  int cnt = t - s;
  int tid = threadIdx.x, wv = tid >> 6, lane = tid & 63;
  __shared__ float lm[4], ls[4];
  __shared__ float lr[4][512];

  float hsr[8];
  {
    float4 q0 = *(const float4*)(hs + (size_t)g * 512 + lane * 8);
    float4 q1 = *(const float4*)(hs + (size_t)g * 512 + lane * 8 + 4);
    hsr[0] = q0.x; hsr[1] = q0.y; hsr[2] = q0.z; hsr[3] = q0.w;
    hsr[4] = q1.x; hsr[5] = q1.y; hsr[6] = q1.z; hsr[7] = q1.w;
  }
  float m = -INFINITY, ssum = 0.f;
  float racc[8] = {};
  for (int i = wv; i < cnt; i += 4) {
    f16x8 rv = *(const f16x8*)(H2 + (size_t)(s + i) * DH + lane * 8);
    float e = 0.f;
#pragma unroll
    for (int k = 0; k < 8; ++k) e += (float)rv[k] * hsr[k];
#pragma unroll
    for (int o = 1; o < 64; o <<= 1) e += __shfl_xor(e, o);
    float mn = fmaxf(m, e);
    float scale = expf(m - mn);   // first iter: exp(-inf)=0
    float p = expf(e - mn);
    ssum = ssum * scale + p;
#pragma unroll
    for (int k = 0; k < 8; ++k) racc[k] = racc[k] * scale + p * (float)rv[k];
    m = mn;
  }
  if (lane == 0) { lm[wv] = m; ls[wv] = ssum; }
#pragma unroll
  for (int k = 0; k < 8; ++k) lr[wv][lane * 8 + k] = racc[k];
  __syncthreads();
  float M = fmaxf(fmaxf(lm[0], lm[1]), fmaxf(lm[2], lm[3]));
  if (!(M > -3.0e38f)) M = 0.f;  // empty graph
  float sc0 = expf(lm[0] - M), sc1 = expf(lm[1] - M);
  float sc2 = expf(lm[2] - M), sc3 = expf(lm[3] - M);
  float denom = ls[0] * sc0 + ls[1] * sc1 + ls[2] * sc2 + ls[3] * sc3;
  float inv = 1.f / fmaxf(denom, 1e-12f);
  int f = tid << 1;
  float r0 = (lr[0][f] * sc0 + lr[1][f] * sc1 + lr[2][f] * sc2 + lr[3][f] * sc3) * inv;
  float r1 = (lr[0][f + 1] * sc0 + lr[1][f + 1] * sc1 + lr[2][f + 1] * sc2 + lr[3][f + 1] * sc3) * inv;
  qstar[(size_t)g * 1024 + 512 + f] = r0;
  qstar[(size_t)g * 1024 + 513 + f] = r1;
  u16 h0, l0, h1, l1;
  split2(r0, h0, l0); split2(r1, h1, l1);
  size_t q = (size_t)g * 1024 + 512 + f;
  qhhi[q] = h0;     qhlo[q] = l0;
  qhhi[q + 1] = h1; qhlo[q + 1] = l1;
}

// ---------------- launch ----------------
extern "C" void kernel_launch(void* const* d_in, const int* in_sizes, int n_in,
                              void* d_out, int out_size, void* d_ws, size_t ws_size,
                              hipStream_t stream) {
  const float* x     = (const float*)d_in[0];
  const int*   ei    = (const int*)d_in[1];
  const int*   batch = (const int*)d_in[2];
  const float* W1    = (const float*)d_in[3];
  const float* b1    = (const float*)d_in[4];
  const float* W2    = (const float*)d_in[5];
  const float* b2    = (const float*)d_in[6];
  const float* W_ih  = (const float*)d_in[7];
  const float* W_hh  = (const float*)d_in[8];
  const float* b_ih  = (const float*)d_in[9];
  const float* b_hh  = (const float*)d_in[10];
  float* qstar = (float*)d_out;

  char* w = (char*)d_ws;
  size_t off = 0;
  auto carve = [&](size_t bytes) -> void* {
    void* p = w + off;
    off += (bytes + 255) & ~(size_t)255;
    return p;
  };
  f16* xh      = (f16*)carve((size_t)NN * DIN * 2);
  u16* axhi    = (u16*)carve((size_t)NN * DIN * 2);
  u16* axlo    = (u16*)carve((size_t)NN * DIN * 2);
  u16* h1hi    = (u16*)carve((size_t)NN * DH * 2);
  u16* h1lo    = (u16*)carve((size_t)NN * DH * 2);
  f16* t2h     = (f16*)carve((size_t)NN * DH * 2);
  f16* H2h     = (f16*)carve((size_t)NN * DH * 2);
  u16* w1thi   = (u16*)carve((size_t)DH * DIN * 2);
  u16* w1tlo   = (u16*)carve((size_t)DH * DIN * 2);
  u16* w2thi   = (u16*)carve((size_t)DH * DH * 2);
  u16* w2tlo   = (u16*)carve((size_t)DH * DH * 2);
  u16* wghi    = (u16*)carve((size_t)2048 * 1024 * 2);
  u16* wglo    = (u16*)carve((size_t)2048 * 1024 * 2);
  u16* qhhi    = (u16*)carve((size_t)NG * 1024 * 2);
  u16* qhlo    = (u16*)carve((size_t)NG * 1024 * 2);
  float* gp    = (float*)carve((size_t)4 * NG * 2048 * 4);
  int* counts  = (int*)carve((size_t)NN * 4);
  int* offs    = (int*)carve((size_t)(NN + 1) * 4);
  int* cursor  = (int*)carve((size_t)NN * 4);
  int* csr     = (int*)carve((size_t)NE * 4);
  float* dinv  = (float*)carve((size_t)NN * 4);
  float* hs    = (float*)carve((size_t)NG * DOUT * 4);
  float* cs    = (float*)carve((size_t)NG * DOUT * 4);
  int* starts  = (int*)carve((size_t)(NG + 1) * 4);

  hipMemsetAsync(counts, 0, (size_t)NN * 4, stream);
  hipMemsetAsync(cursor, 0, (size_t)NN * 4, stream);
  hipMemsetAsync(hs, 0, (size_t)NG * DOUT * 4, stream);
  hipMemsetAsync(cs, 0, (size_t)NG * DOUT * 4, stream);
  hipMemsetAsync(qstar, 0, (size_t)NG * 1024 * 4, stream);
  hipMemsetAsync(qhhi, 0, (size_t)NG * 1024 * 2, stream);
  hipMemsetAsync(qhlo, 0, (size_t)NG * 1024 * 2, stream);

  k_count<<<NE / 256, 256, 0, stream>>>(ei, counts);
  k_scan<<<1, 1024, 0, stream>>>(counts, offs);
  k_fill<<<NE / 256, 256, 0, stream>>>(ei, offs, cursor, csr);
  k_dinv<<<NN / 256, 256, 0, stream>>>(counts, dinv);
  k_starts<<<1, NG, 0, stream>>>(batch, starts);

  k_half<<<NN * DIN / 1024, 256, 0, stream>>>(x, xh);
  k_split_t<<<(DIN * DH + 255) / 256, 256, 0, stream>>>(W1, w1thi, w1tlo, DIN, DH, DIN * DH);
  k_split_t<<<(DH * DH + 255) / 256, 256, 0, stream>>>(W2, w2thi, w2tlo, DH, DH, DH * DH);
  k_wc<<<(2048 * 1024) / 256, 256, 0, stream>>>(W_ih, W_hh, wghi, wglo);

  // layer 1: aggx = Agg(x) ; H1 = relu(aggx@W1 + b1)
  k_agg256<<<NN / 4, 256, 0, stream>>>(xh, offs, csr, dinv, axhi, axlo);
  k_mfma_gemm<1><<<(NN / 128) * (DH / 128), 256, 0, stream>>>(
      axhi, axlo, w1thi, w1tlo, nullptr, h1hi, h1lo, nullptr, b1, NN, DH, DIN, DIN, DIN);
  // layer 2: t2 = H1@W2 ; H2 = Agg(t2) + b2
  k_mfma_gemm<2><<<(NN / 128) * (DH / 128), 256, 0, stream>>>(
      h1hi, h1lo, w2thi, w2tlo, nullptr, nullptr, nullptr, t2h, nullptr, NN, DH, DH, DH, DH);
  k_agg512<<<NN / 4, 256, 0, stream>>>(t2h, offs, csr, dinv, b2, H2h);

  for (int step = 0; step < 3; ++step) {
    // gates partials: 4 K-slices of 256 in one dispatch (grid 128)
    k_mfma_gemm<0><<<4 * (NG / 128) * (2048 / 128), 256, 0, stream>>>(
        qhhi, qhlo, wghi, wglo, gp, nullptr, nullptr, nullptr, nullptr,
        NG, 2048, 256, 1024, 1024);
    k_lstm<<<(NG * DOUT) / 256, 256, 0, stream>>>(gp, b_ih, b_hh, cs, hs, qstar, qhhi, qhlo);
    k_pool<<<NG, 256, 0, stream>>>(H2h, hs, starts, qstar, qhhi, qhlo);
  }
}

// Round 6
// 343.336 us; speedup vs baseline: 3.3599x; 1.0563x over previous
//
#include <hip/hip_runtime.h>
#include <math.h>

#define NN 32768
#define NE 262144
#define NG 256
#define DIN 256
#define DH 512
#define DOUT 512

typedef unsigned short u16;
typedef _Float16 f16;
typedef __attribute__((ext_vector_type(4))) _Float16 f16x4;
typedef __attribute__((ext_vector_type(8))) _Float16 f16x8;
typedef __attribute__((ext_vector_type(8))) short short8;
typedef __attribute__((ext_vector_type(4))) float f32x4;

__device__ inline u16 bf16rn(float f) {
  unsigned u = __float_as_uint(f);
  return (u16)((u + 0x7fff + ((u >> 16) & 1)) >> 16);
}
__device__ inline float bfbits(u16 b) { return __uint_as_float(((unsigned)b) << 16); }
__device__ inline void split2(float f, u16& h, u16& l) {
  h = bf16rn(f);
  float r = f - bfbits(h);
  l = bf16rn(r);
}

__device__ inline void gload16(const void* g, void* l) {
  __builtin_amdgcn_global_load_lds((const __attribute__((address_space(1))) unsigned int*)g,
                                   (__attribute__((address_space(3))) unsigned int*)l,
                                   16, 0, 0);
}

// ---------------- graph prep ----------------

__global__ void k_count(const int* __restrict__ ei, int* __restrict__ counts) {
  int e = blockIdx.x * 256 + threadIdx.x;
  if (e < NE) atomicAdd(&counts[ei[NE + e]], 1);
}

// hierarchical scan: A) per-block reduce, B) scan of block sums, C) apply + local scan + dinv
__global__ __launch_bounds__(128) void k_scanA(const int* __restrict__ counts,
                                               int* __restrict__ bsum) {
  int b = blockIdx.x, t = threadIdx.x;
  int v = counts[b * 128 + t];
  __shared__ int red[128];
  red[t] = v;
  __syncthreads();
#pragma unroll
  for (int o = 64; o > 0; o >>= 1) {
    if (t < o) red[t] += red[t + o];
    __syncthreads();
  }
  if (t == 0) bsum[b] = red[0];
}

__global__ __launch_bounds__(256) void k_scanB(const int* __restrict__ bsum,
                                               int* __restrict__ boff,
                                               int* __restrict__ offs) {
  __shared__ int s[256];
  int t = threadIdx.x;
  int v = bsum[t];
  s[t] = v;
  __syncthreads();
  for (int o = 1; o < 256; o <<= 1) {
    int add = (t >= o) ? s[t - o] : 0;
    __syncthreads();
    s[t] += add;
    __syncthreads();
  }
  boff[t] = s[t] - v;  // exclusive
  if (t == 255) offs[NN] = s[255];
}

__global__ __launch_bounds__(128) void k_scanC(const int* __restrict__ counts,
                                               const int* __restrict__ boff,
                                               int* __restrict__ offs,
                                               float* __restrict__ dinv) {
  int b = blockIdx.x, t = threadIdx.x;
  int v = counts[b * 128 + t];
  __shared__ int s[128];
  s[t] = v;
  __syncthreads();
  for (int o = 1; o < 128; o <<= 1) {
    int add = (t >= o) ? s[t - o] : 0;
    __syncthreads();
    s[t] += add;
    __syncthreads();
  }
  offs[b * 128 + t] = boff[b] + s[t] - v;
  dinv[b * 128 + t] = rsqrtf((float)(v + 1));
}

__global__ void k_fill(const int* __restrict__ ei, const int* __restrict__ offs,
                       int* __restrict__ cursor, int* __restrict__ csr) {
  int e = blockIdx.x * 256 + threadIdx.x;
  if (e < NE) {
    int d = ei[NE + e];
    int pos = offs[d] + atomicAdd(&cursor[d], 1);
    csr[pos] = ei[e];
  }
}

__global__ void k_starts(const int* __restrict__ batch, int* __restrict__ starts) {
  int g = threadIdx.x;
  int lo = 0, hi = NN;
  while (lo < hi) {
    int mid = (lo + hi) >> 1;
    if (batch[mid] < g) lo = mid + 1; else hi = mid;
  }
  starts[g] = lo;
  if (g == 0) starts[NG] = NN;
}

// ---------------- conversions / weight prep ----------------

__global__ void k_half(const float* __restrict__ src, f16* __restrict__ dst) {
  int i = (blockIdx.x * 256 + threadIdx.x) << 2;
  float4 v = *(const float4*)(src + i);
  f16x4 h = {(f16)v.x, (f16)v.y, (f16)v.z, (f16)v.w};
  *(f16x4*)(dst + i) = h;
}

// transpose split: src [K][N] fp32 -> dst [N][K] bf16 hi/lo
__global__ void k_split_t(const float* __restrict__ src, u16* __restrict__ hi, u16* __restrict__ lo,
                          int K, int N, int total) {
  int idx = blockIdx.x * 256 + threadIdx.x;
  if (idx >= total) return;
  int k = idx / N, n = idx - k * N;
  u16 h, l;
  split2(src[idx], h, l);
  size_t d = (size_t)n * K + k;
  hi[d] = h; lo[d] = l;
}

// combined gates weight: wg[n][c] = (c<512 ? W_ih[n][c]+W_hh[n][c] : W_ih[n][c]), split hi/lo
__global__ void k_wc(const float* __restrict__ W_ih, const float* __restrict__ W_hh,
                     u16* __restrict__ wghi, u16* __restrict__ wglo) {
  int idx = blockIdx.x * 256 + threadIdx.x;  // 2048*1024
  int n = idx >> 10, c = idx & 1023;
  float v = W_ih[(size_t)n * 1024 + c];
  if (c < 512) v += W_hh[(size_t)n * 512 + c];
  u16 h, l;
  split2(v, h, l);
  wghi[idx] = h; wglo[idx] = l;
}

// ---------------- split-bf16 MFMA GEMM (round-4 structure: BK=64, single buffer) ----------------
// C[M][N] = A[M][K'] @ Bt[N][K']^T over K elems at koff = slice*K (split-K).
// MODE 0: fp32 C partial at slice*M*N. MODE 1: +bias, relu, split->Chi/Clo. MODE 2: f16 out.
template <int MODE>
__global__ __launch_bounds__(256) void k_mfma_gemm(
    const u16* __restrict__ Ahi, const u16* __restrict__ Alo,
    const u16* __restrict__ Bhi, const u16* __restrict__ Blo,
    float* __restrict__ C, u16* __restrict__ Chi, u16* __restrict__ Clo,
    f16* __restrict__ Cf16, const float* __restrict__ bias,
    int M, int N, int K, int lda, int ldb) {
  __shared__ char lds[65536];  // Ahi 16K | Alo 16K | Bhi 16K | Blo 16K

  int nbn = N >> 7;
  int nwg = (M >> 7) * nbn;
  int b = blockIdx.x;
  int slice = b / nwg;
  b -= slice * nwg;
  int koff = slice * K;
  int swz = (b & 7) * (nwg >> 3) + (b >> 3);  // nwg % 8 == 0 for all our shapes
  int bn = (swz % nbn) << 7;
  int bm = (swz / nbn) << 7;

  int tid = threadIdx.x;
  int w = tid >> 6, lane = tid & 63;
  int wm = (w >> 1) << 6, wn = (w & 1) << 6;
  int fr = lane & 15;
  int fq = lane >> 4;

  f32x4 acc[4][4];
#pragma unroll
  for (int i = 0; i < 4; ++i)
#pragma unroll
    for (int j = 0; j < 4; ++j) acc[i][j] = (f32x4){0.f, 0.f, 0.f, 0.f};

  for (int ks = 0; ks < K; ks += 64) {
#pragma unroll
    for (int i = 0; i < 4; ++i) {
      int L = i * 256 + tid;
      int row = L >> 3;
      int ke = ((L & 7) ^ (row & 7)) << 3;  // pre-swizzled global source
      int ldsoff = i * 4096 + w * 1024;     // wave-uniform base (+lane*16 by HW)
      gload16(Ahi + (size_t)(bm + row) * lda + koff + ks + ke, lds + ldsoff);
      gload16(Alo + (size_t)(bm + row) * lda + koff + ks + ke, lds + 16384 + ldsoff);
      gload16(Bhi + (size_t)(bn + row) * ldb + koff + ks + ke, lds + 32768 + ldsoff);
      gload16(Blo + (size_t)(bn + row) * ldb + koff + ks + ke, lds + 49152 + ldsoff);
    }
    __syncthreads();
#pragma unroll
    for (int kk = 0; kk < 2; ++kk) {
      short8 ah[4], al[4], bh[4], bl[4];
#pragma unroll
      for (int m = 0; m < 4; ++m) {
        int row = wm + m * 16 + fr;
        int boff = row * 128 + (((kk << 6) + (fq << 4)) ^ ((row & 7) << 4));
        ah[m] = *(const short8*)(lds + boff);
        al[m] = *(const short8*)(lds + 16384 + boff);
      }
#pragma unroll
      for (int n = 0; n < 4; ++n) {
        int row = wn + n * 16 + fr;
        int boff = row * 128 + (((kk << 6) + (fq << 4)) ^ ((row & 7) << 4));
        bh[n] = *(const short8*)(lds + 32768 + boff);
        bl[n] = *(const short8*)(lds + 49152 + boff);
      }
#pragma unroll
      for (int m = 0; m < 4; ++m)
#pragma unroll
        for (int n = 0; n < 4; ++n) {
          acc[m][n] = __builtin_amdgcn_mfma_f32_16x16x32_bf16(ah[m], bh[n], acc[m][n], 0, 0, 0);
          acc[m][n] = __builtin_amdgcn_mfma_f32_16x16x32_bf16(ah[m], bl[n], acc[m][n], 0, 0, 0);
          acc[m][n] = __builtin_amdgcn_mfma_f32_16x16x32_bf16(al[m], bh[n], acc[m][n], 0, 0, 0);
        }
    }
    __syncthreads();
  }
#pragma unroll
  for (int m = 0; m < 4; ++m)
#pragma unroll
    for (int n = 0; n < 4; ++n)
#pragma unroll
      for (int i = 0; i < 4; ++i) {
        int r = bm + wm + m * 16 + fq * 4 + i;
        int c = bn + wn + n * 16 + fr;
        float val = acc[m][n][i];
        if (MODE == 1) {
          val += bias[c];
          val = fmaxf(val, 0.f);
          u16 h, l;
          split2(val, h, l);
          Chi[(size_t)r * N + c] = h;
          Clo[(size_t)r * N + c] = l;
        } else if (MODE == 2) {
          Cf16[(size_t)r * N + c] = (f16)val;
        } else {
          C[(size_t)slice * M * N + (size_t)r * N + c] = val;
        }
      }
}

// ---------------- aggregation, 256-dim fp16 -> bf16 hi/lo. One wave per node, ILP-4. ----------------
__global__ __launch_bounds__(256) void k_agg256(const f16* __restrict__ xh,
                                                const int* __restrict__ offs,
                                                const int* __restrict__ csr,
                                                const float* __restrict__ dinv,
                                                u16* __restrict__ ohi, u16* __restrict__ olo) {
  int wv = threadIdx.x >> 6, lane = threadIdx.x & 63;
  int v = blockIdx.x * 4 + wv;
  int f = lane << 2;
  int s = offs[v], t = offs[v + 1];
  float dv = dinv[v];
  float a0[4] = {}, a1[4] = {}, a2[4] = {}, a3[4] = {};
  for (int base = s; base < t; base += 64) {
    int rem = min(64, t - base);
    int idx = (lane < rem) ? csr[base + lane] : 0;
    float wl = (lane < rem) ? dinv[idx] : 0.f;
    int i = 0;
    for (; i + 3 < rem; i += 4) {
      int u0 = __shfl(idx, i), u1 = __shfl(idx, i + 1);
      int u2 = __shfl(idx, i + 2), u3 = __shfl(idx, i + 3);
      float w0 = __shfl(wl, i), w1 = __shfl(wl, i + 1);
      float w2 = __shfl(wl, i + 2), w3 = __shfl(wl, i + 3);
      f16x4 r0 = *(const f16x4*)(xh + (size_t)u0 * DIN + f);
      f16x4 r1 = *(const f16x4*)(xh + (size_t)u1 * DIN + f);
      f16x4 r2 = *(const f16x4*)(xh + (size_t)u2 * DIN + f);
      f16x4 r3 = *(const f16x4*)(xh + (size_t)u3 * DIN + f);
#pragma unroll
      for (int k = 0; k < 4; ++k) {
        a0[k] += w0 * (float)r0[k]; a1[k] += w1 * (float)r1[k];
        a2[k] += w2 * (float)r2[k]; a3[k] += w3 * (float)r3[k];
      }
    }
    for (; i < rem; ++i) {
      int u0 = __shfl(idx, i);
      float w0 = __shfl(wl, i);
      f16x4 r0 = *(const f16x4*)(xh + (size_t)u0 * DIN + f);
#pragma unroll
      for (int k = 0; k < 4; ++k) a0[k] += w0 * (float)r0[k];
    }
  }
  f16x4 rs = *(const f16x4*)(xh + (size_t)v * DIN + f);
  u16 h[4], l[4];
#pragma unroll
  for (int k = 0; k < 4; ++k) {
    float r = (a0[k] + a1[k] + a2[k] + a3[k] + dv * (float)rs[k]) * dv;
    split2(r, h[k], l[k]);
  }
  uint2 vh = {(unsigned)h[0] | ((unsigned)h[1] << 16), (unsigned)h[2] | ((unsigned)h[3] << 16)};
  uint2 vl = {(unsigned)l[0] | ((unsigned)l[1] << 16), (unsigned)l[2] | ((unsigned)l[3] << 16)};
  *(uint2*)(ohi + (size_t)v * DIN + f) = vh;
  *(uint2*)(olo + (size_t)v * DIN + f) = vl;
}

// ---------------- aggregation, 512-dim fp16 + bias -> fp16. One wave per node, ILP-4. ----------------
__global__ __launch_bounds__(256) void k_agg512(const f16* __restrict__ T2,
                                                const int* __restrict__ offs,
                                                const int* __restrict__ csr,
                                                const float* __restrict__ dinv,
                                                const float* __restrict__ bias,
                                                f16* __restrict__ H2) {
  int wv = threadIdx.x >> 6, lane = threadIdx.x & 63;
  int v = blockIdx.x * 4 + wv;
  int f = lane << 3;
  int s = offs[v], t = offs[v + 1];
  float dv = dinv[v];
  float a0[8] = {}, a1[8] = {}, a2[8] = {}, a3[8] = {};
  for (int base = s; base < t; base += 64) {
    int rem = min(64, t - base);
    int idx = (lane < rem) ? csr[base + lane] : 0;
    float wl = (lane < rem) ? dinv[idx] : 0.f;
    int i = 0;
    for (; i + 3 < rem; i += 4) {
      int u0 = __shfl(idx, i), u1 = __shfl(idx, i + 1);
      int u2 = __shfl(idx, i + 2), u3 = __shfl(idx, i + 3);
      float w0 = __shfl(wl, i), w1 = __shfl(wl, i + 1);
      float w2 = __shfl(wl, i + 2), w3 = __shfl(wl, i + 3);
      f16x8 r0 = *(const f16x8*)(T2 + (size_t)u0 * DH + f);
      f16x8 r1 = *(const f16x8*)(T2 + (size_t)u1 * DH + f);
      f16x8 r2 = *(const f16x8*)(T2 + (size_t)u2 * DH + f);
      f16x8 r3 = *(const f16x8*)(T2 + (size_t)u3 * DH + f);
#pragma unroll
      for (int k = 0; k < 8; ++k) {
        a0[k] += w0 * (float)r0[k]; a1[k] += w1 * (float)r1[k];
        a2[k] += w2 * (float)r2[k]; a3[k] += w3 * (float)r3[k];
      }
    }
    for (; i < rem; ++i) {
      int u0 = __shfl(idx, i);
      float w0 = __shfl(wl, i);
      f16x8 r0 = *(const f16x8*)(T2 + (size_t)u0 * DH + f);
#pragma unroll
      for (int k = 0; k < 8; ++k) a0[k] += w0 * (float)r0[k];
    }
  }
  f16x8 rs = *(const f16x8*)(T2 + (size_t)v * DH + f);
  float4 bb0 = *(const float4*)(bias + f);
  float4 bb1 = *(const float4*)(bias + f + 4);
  float bbv[8] = {bb0.x, bb0.y, bb0.z, bb0.w, bb1.x, bb1.y, bb1.z, bb1.w};
  f16x8 out;
#pragma unroll
  for (int k = 0; k < 8; ++k)
    out[k] = (f16)((a0[k] + a1[k] + a2[k] + a3[k] + dv * (float)rs[k]) * dv + bbv[k]);
  *(f16x8*)(H2 + (size_t)v * DH + f) = out;
}

// ---------------- fused set2set step: LSTM (from 4 split-K partials) + flash pool ----------------
// One block per graph. LSTM phase -> hs in LDS; pool phase reads hs from LDS.
__global__ __launch_bounds__(256) void k_step(const float* __restrict__ gp,
                                              const float* __restrict__ b_ih,
                                              const float* __restrict__ b_hh,
                                              float* __restrict__ cs,
                                              const f16* __restrict__ H2,
                                              const int* __restrict__ starts,
                                              float* __restrict__ qstar,
                                              u16* __restrict__ qhhi, u16* __restrict__ qhlo) {
  int g = blockIdx.x;
  int tid = threadIdx.x, wv = tid >> 6, lane = tid & 63;
  __shared__ float shs[512];
  __shared__ float lm[4], lsum[4];
  __shared__ float lr[4][512];

  // --- LSTM phase: each thread handles j = tid and tid+256 ---
  const float* g0 = gp + (size_t)g * 2048;
#pragma unroll
  for (int jj = 0; jj < 2; ++jj) {
    int j = tid + jj * 256;
    float iv = b_ih[j]        + b_hh[j];
    float fv = b_ih[512 + j]  + b_hh[512 + j];
    float gv = b_ih[1024 + j] + b_hh[1024 + j];
    float ov = b_ih[1536 + j] + b_hh[1536 + j];
#pragma unroll
    for (int sl = 0; sl < 4; ++sl) {
      const float* gs = g0 + (size_t)sl * 524288;
      iv += gs[j]; fv += gs[512 + j]; gv += gs[1024 + j]; ov += gs[1536 + j];
    }
    float si = 1.f / (1.f + expf(-iv));
    float sf = 1.f / (1.f + expf(-fv));
    float so = 1.f / (1.f + expf(-ov));
    float c = sf * cs[(size_t)g * 512 + j] + si * tanhf(gv);
    float h = so * tanhf(c);
    cs[(size_t)g * 512 + j] = c;
    shs[j] = h;
    qstar[(size_t)g * 1024 + j] = h;
    u16 hh, hl;
    split2(h, hh, hl);
    qhhi[(size_t)g * 1024 + j] = hh;
    qhlo[(size_t)g * 1024 + j] = hl;
  }
  __syncthreads();

  // --- pool phase ---
  int s = starts[g], t = starts[g + 1];
  int cnt = t - s;
  float hsr[8];
#pragma unroll
  for (int k = 0; k < 8; ++k) hsr[k] = shs[lane * 8 + k];

  float m = -INFINITY, ssum = 0.f;
  float racc[8] = {};
  for (int i = wv; i < cnt; i += 4) {
    f16x8 rv = *(const f16x8*)(H2 + (size_t)(s + i) * DH + lane * 8);
    float e = 0.f;
#pragma unroll
    for (int k = 0; k < 8; ++k) e += (float)rv[k] * hsr[k];
#pragma unroll
    for (int o = 1; o < 64; o <<= 1) e += __shfl_xor(e, o);
    float mn = fmaxf(m, e);
    float scale = expf(m - mn);   // first iter: exp(-inf)=0
    float p = expf(e - mn);
    ssum = ssum * scale + p;
#pragma unroll
    for (int k = 0; k < 8; ++k) racc[k] = racc[k] * scale + p * (float)rv[k];
    m = mn;
  }
  if (lane == 0) { lm[wv] = m; lsum[wv] = ssum; }
#pragma unroll
  for (int k = 0; k < 8; ++k) lr[wv][lane * 8 + k] = racc[k];
  __syncthreads();
  float M = fmaxf(fmaxf(lm[0], lm[1]), fmaxf(lm[2], lm[3]));
  if (!(M > -3.0e38f)) M = 0.f;  // empty graph
  float sc0 = expf(lm[0] - M), sc1 = expf(lm[1] - M);
  float sc2 = expf(lm[2] - M), sc3 = expf(lm[3] - M);
  float denom = lsum[0] * sc0 + lsum[1] * sc1 + lsum[2] * sc2 + lsum[3] * sc3;
  float inv = 1.f / fmaxf(denom, 1e-12f);
  int f = tid << 1;
  float r0 = (lr[0][f] * sc0 + lr[1][f] * sc1 + lr[2][f] * sc2 + lr[3][f] * sc3) * inv;
  float r1 = (lr[0][f + 1] * sc0 + lr[1][f + 1] * sc1 + lr[2][f + 1] * sc2 + lr[3][f + 1] * sc3) * inv;
  qstar[(size_t)g * 1024 + 512 + f] = r0;
  qstar[(size_t)g * 1024 + 513 + f] = r1;
  u16 h0, l0, h1, l1;
  split2(r0, h0, l0); split2(r1, h1, l1);
  size_t q = (size_t)g * 1024 + 512 + f;
  qhhi[q] = h0;     qhlo[q] = l0;
  qhhi[q + 1] = h1; qhlo[q + 1] = l1;
}

// ---------------- launch ----------------
extern "C" void kernel_launch(void* const* d_in, const int* in_sizes, int n_in,
                              void* d_out, int out_size, void* d_ws, size_t ws_size,
                              hipStream_t stream) {
  const float* x     = (const float*)d_in[0];
  const int*   ei    = (const int*)d_in[1];
  const int*   batch = (const int*)d_in[2];
  const float* W1    = (const float*)d_in[3];
  const float* b1    = (const float*)d_in[4];
  const float* W2    = (const float*)d_in[5];
  const float* b2    = (const float*)d_in[6];
  const float* W_ih  = (const float*)d_in[7];
  const float* W_hh  = (const float*)d_in[8];
  const float* b_ih  = (const float*)d_in[9];
  const float* b_hh  = (const float*)d_in[10];
  float* qstar = (float*)d_out;

  char* w = (char*)d_ws;
  size_t off = 0;
  auto carve = [&](size_t bytes) -> void* {
    void* p = w + off;
    off += (bytes + 255) & ~(size_t)255;
    return p;
  };
  f16* xh      = (f16*)carve((size_t)NN * DIN * 2);
  u16* axhi    = (u16*)carve((size_t)NN * DIN * 2);
  u16* axlo    = (u16*)carve((size_t)NN * DIN * 2);
  u16* h1hi    = (u16*)carve((size_t)NN * DH * 2);
  u16* h1lo    = (u16*)carve((size_t)NN * DH * 2);
  f16* t2h     = (f16*)carve((size_t)NN * DH * 2);
  f16* H2h     = (f16*)carve((size_t)NN * DH * 2);
  u16* w1thi   = (u16*)carve((size_t)DH * DIN * 2);
  u16* w1tlo   = (u16*)carve((size_t)DH * DIN * 2);
  u16* w2thi   = (u16*)carve((size_t)DH * DH * 2);
  u16* w2tlo   = (u16*)carve((size_t)DH * DH * 2);
  u16* wghi    = (u16*)carve((size_t)2048 * 1024 * 2);
  u16* wglo    = (u16*)carve((size_t)2048 * 1024 * 2);
  u16* qhhi    = (u16*)carve((size_t)NG * 1024 * 2);
  u16* qhlo    = (u16*)carve((size_t)NG * 1024 * 2);
  float* gp    = (float*)carve((size_t)4 * NG * 2048 * 4);
  int* counts  = (int*)carve((size_t)NN * 4);
  int* offs    = (int*)carve((size_t)(NN + 1) * 4);
  int* cursor  = (int*)carve((size_t)NN * 4);
  int* csr     = (int*)carve((size_t)NE * 4);
  float* dinv  = (float*)carve((size_t)NN * 4);
  float* cs    = (float*)carve((size_t)NG * DOUT * 4);
  int* starts  = (int*)carve((size_t)(NG + 1) * 4);
  int* bsum    = (int*)carve((size_t)256 * 4);
  int* boff    = (int*)carve((size_t)256 * 4);

  hipMemsetAsync(counts, 0, (size_t)NN * 4, stream);
  hipMemsetAsync(cursor, 0, (size_t)NN * 4, stream);
  hipMemsetAsync(cs, 0, (size_t)NG * DOUT * 4, stream);
  hipMemsetAsync(qstar, 0, (size_t)NG * 1024 * 4, stream);
  hipMemsetAsync(qhhi, 0, (size_t)NG * 1024 * 2, stream);
  hipMemsetAsync(qhlo, 0, (size_t)NG * 1024 * 2, stream);

  k_count<<<NE / 256, 256, 0, stream>>>(ei, counts);
  k_scanA<<<NN / 128, 128, 0, stream>>>(counts, bsum);
  k_scanB<<<1, 256, 0, stream>>>(bsum, boff, offs);
  k_scanC<<<NN / 128, 128, 0, stream>>>(counts, boff, offs, dinv);
  k_fill<<<NE / 256, 256, 0, stream>>>(ei, offs, cursor, csr);
  k_starts<<<1, NG, 0, stream>>>(batch, starts);

  k_half<<<NN * DIN / 1024, 256, 0, stream>>>(x, xh);
  k_split_t<<<(DIN * DH + 255) / 256, 256, 0, stream>>>(W1, w1thi, w1tlo, DIN, DH, DIN * DH);
  k_split_t<<<(DH * DH + 255) / 256, 256, 0, stream>>>(W2, w2thi, w2tlo, DH, DH, DH * DH);
  k_wc<<<(2048 * 1024) / 256, 256, 0, stream>>>(W_ih, W_hh, wghi, wglo);

  // layer 1: aggx = Agg(x) ; H1 = relu(aggx@W1 + b1)
  k_agg256<<<NN / 4, 256, 0, stream>>>(xh, offs, csr, dinv, axhi, axlo);
  k_mfma_gemm<1><<<(NN / 128) * (DH / 128), 256, 0, stream>>>(
      axhi, axlo, w1thi, w1tlo, nullptr, h1hi, h1lo, nullptr, b1, NN, DH, DIN, DIN, DIN);
  // layer 2: t2 = H1@W2 ; H2 = Agg(t2) + b2
  k_mfma_gemm<2><<<(NN / 128) * (DH / 128), 256, 0, stream>>>(
      h1hi, h1lo, w2thi, w2tlo, nullptr, nullptr, nullptr, t2h, nullptr, NN, DH, DH, DH, DH);
  k_agg512<<<NN / 4, 256, 0, stream>>>(t2h, offs, csr, dinv, b2, H2h);

  for (int step = 0; step < 3; ++step) {
    // gates partials: 4 K-slices of 256 in one dispatch (grid 128)
    k_mfma_gemm<0><<<4 * (NG / 128) * (2048 / 128), 256, 0, stream>>>(
        qhhi, qhlo, wghi, wglo, gp, nullptr, nullptr, nullptr, nullptr,
        NG, 2048, 256, 1024, 1024);
    k_step<<<NG, 256, 0, stream>>>(gp, b_ih, b_hh, cs, H2h, starts, qstar, qhhi, qhlo);
  }
}